// Round 4
// baseline (192.896 us; speedup 1.0000x reference)
//
#include <hip/hip_runtime.h>
#include <hip/hip_fp16.h>
#include <cmath>

#define DIM_M 1024   // B (batch)
#define DIM_K 8192   // D
#define DIM_N 4096   // U
#define SPLIT 4
#define KSPL  (DIM_K / SPLIT)   // 2048
#define BKT   64
#define NT    (KSPL / BKT)      // 32 K-tiles per block

typedef __attribute__((ext_vector_type(8))) _Float16 half8;
typedef __attribute__((ext_vector_type(4))) float floatx4;
typedef __attribute__((ext_vector_type(4))) int intx4;

struct __align__(8) Half4 { __half2 a, b; };

__device__ inline void gload_lds16(const void* g, void* l) {
    __builtin_amdgcn_global_load_lds(
        (const __attribute__((address_space(1))) void*)g,
        (__attribute__((address_space(3))) void*)l, 16, 0, 0);
}

__global__ void zero_f4(floatx4* __restrict__ p, int n4) {
    int i = blockIdx.x * blockDim.x + threadIdx.x;
    if (i < n4) p[i] = floatx4{0.f, 0.f, 0.f, 0.f};
}

// scatter into fp16 W^T [N][K]: wh[u*K + d] += v, 4 entries/thread,
// native global_atomic_pk_add_f16 via inline asm (no CAS loop, no return-wait)
__global__ void scatter_h(const int* __restrict__ ind, const float* __restrict__ kv,
                          _Float16* __restrict__ wh, int nnz) {
    const int base = (blockIdx.x * blockDim.x + threadIdx.x) * 4;
    if (base >= nnz) return;
    // 4 entries: ind[2*base .. 2*base+7] = two int4, kv[base..base+3] = one float4
    intx4 i01 = *(const intx4*)(ind + 2 * (size_t)base);
    intx4 i23 = *(const intx4*)(ind + 2 * (size_t)base + 4);
    floatx4 v4 = *(const floatx4*)(kv + base);
    int dd[4] = { i01.x, i01.z, i23.x, i23.z };
    int uu[4] = { i01.y, i01.w, i23.y, i23.w };
    #pragma unroll
    for (int j = 0; j < 4; ++j) {
        if (base + j < nnz) {
            size_t idx = (size_t)uu[j] * DIM_K + dd[j];
            unsigned short hv = __half_as_ushort(__float2half(v4[j]));
            unsigned int data = (idx & 1) ? ((unsigned int)hv << 16) : (unsigned int)hv;
            const _Float16* addr = wh + (idx & ~(size_t)1);
            asm volatile("global_atomic_pk_add_f16 %0, %1, off"
                         :: "v"(addr), "v"(data) : "memory");
        }
    }
}

__global__ void cvt_f2h(const floatx4* __restrict__ in, Half4* __restrict__ out, int n4) {
    int i = blockIdx.x * blockDim.x + threadIdx.x;
    if (i < n4) {
        floatx4 f = in[i];
        Half4 h;
        h.a = __floats2half2_rn(f.x, f.y);
        h.b = __floats2half2_rn(f.z, f.w);
        out[i] = h;
    }
}

// ---------------------------------------------------------------------------
// 256x256 8-phase split-K GEMM: part[split][M][N] = A[M][ksl] * B^T[N][ksl]
// 512 thr (8 waves, 2M x 4N), BK=64, dbuf at K-tile level, counted vmcnt(8).
// LDS (dynamic 128KB): buf c: A[256][64]f16 @ c*65536, B[256][64]f16 @ +32768.
// Swizzle: logical 16B-chunk c of row r lives at physical chunk c ^ (r&7);
// applied on the pre-swizzled global source (write side, linear gload_lds
// dest) AND on the ds_read address (read side) — same involution.
// ---------------------------------------------------------------------------
__global__ __launch_bounds__(512, 2) void gemm8_k(
    const _Float16* __restrict__ Ah,   // [M][K] fp16
    const _Float16* __restrict__ Bh,   // [N][K] fp16
    float*          __restrict__ part) // [SPLIT][M][N] fp32
{
    extern __shared__ char smem[];

    const int tid  = threadIdx.x;
    const int lane = tid & 63;
    const int wave = tid >> 6;

    // chunked XCD swizzle (256 blocks, 8 XCDs -> 32 consecutive per XCD):
    // swz layout: n-tile (16) outer, then m-tile (4), split (4).
    const int bid = blockIdx.x;
    const int swz = (bid & 7) * 32 + (bid >> 3);
    const int n0  = (swz >> 4) * 256;
    const int rem = swz & 15;
    const int m0  = (rem >> 2) * 256;
    const int sp  = rem & 3;
    const size_t kbase = (size_t)sp * KSPL;

    // --- staging (write side): thread tid covers LDS row srow+j*64, chunk tid&7;
    // global source chunk pre-swizzled by ^(row&7) = ^(srow&7).
    const int srow = tid >> 3;                   // 0..63
    const int sch  = (tid & 7) ^ (srow & 7);
    const _Float16* aSg = Ah + (size_t)(m0 + srow) * DIM_K + kbase + sch * 8;
    const _Float16* bSg = Bh + (size_t)(n0 + srow) * DIM_K + kbase + sch * 8;
    char* aLg = smem + wave * 1024;
    char* bLg = smem + 32768 + wave * 1024;

    // --- read side: A rows wrm*128 + mi*16 + (lane&15); B rows wn*64 + ni*16 + (lane&15).
    // logical chunk = kk*4 + (lane>>4); XOR term (row&7) == (lane&7).
    const int wn  = wave & 3;
    const int wrm = wave >> 2;
    const int q   = lane >> 4;
    const int l7  = lane & 7;
    const char* aRd = smem + (wrm * 128 + (lane & 15)) * 128;
    const char* bRd = smem + 32768 + (wn * 64 + (lane & 15)) * 128;
    const int ch0 = ((0 * 4 + q) ^ l7) * 16;     // kk = 0
    const int ch1 = ((1 * 4 + q) ^ l7) * 16;     // kk = 1

    floatx4 acc[8][4] = {};
    half8 aF[4], bF[4];

#define STAGE(C)                                                              \
    { _Pragma("unroll") for (int j = 0; j < 4; ++j) {                         \
        gload_lds16(aSg + (size_t)j * (64 * DIM_K), aLg + (C) * 65536 + j * 8192); \
        gload_lds16(bSg + (size_t)j * (64 * DIM_K), bLg + (C) * 65536 + j * 8192); } \
      aSg += BKT; bSg += BKT; }

#define PH(C, MIOFF, CH, RB)                                                  \
    { _Pragma("unroll") for (int i = 0; i < 4; ++i)                           \
        aF[i] = *(const half8*)(aRd + (C) * 65536 + ((MIOFF) + i) * 2048 + (CH)); \
      if (RB) { _Pragma("unroll") for (int i = 0; i < 4; ++i)                 \
        bF[i] = *(const half8*)(bRd + (C) * 65536 + i * 2048 + (CH)); }       \
      __builtin_amdgcn_s_barrier();                                           \
      asm volatile("s_waitcnt lgkmcnt(0)" ::: "memory");                      \
      __builtin_amdgcn_sched_barrier(0);                                      \
      __builtin_amdgcn_s_setprio(1);                                          \
      _Pragma("unroll") for (int mi = 0; mi < 4; ++mi)                        \
        _Pragma("unroll") for (int ni = 0; ni < 4; ++ni)                      \
          acc[(MIOFF) + mi][ni] = __builtin_amdgcn_mfma_f32_16x16x32_f16(     \
              aF[mi], bF[ni], acc[(MIOFF) + mi][ni], 0, 0, 0);                \
      __builtin_amdgcn_s_setprio(0);                                          \
      __builtin_amdgcn_s_barrier(); }

#define KTILE(C) PH(C, 0, ch0, 1) PH(C, 4, ch0, 0) PH(C, 0, ch1, 1) PH(C, 4, ch1, 0)

    // prologue: stage K-tiles 0,1; wait for K-tile 0 (8 newest may fly)
    STAGE(0)
    STAGE(1)
    asm volatile("s_waitcnt vmcnt(8)" ::: "memory");
    __builtin_amdgcn_s_barrier();

    for (int t2 = 0; t2 < NT / 2; ++t2) {
        KTILE(0)                                  // compute K-tile 2*t2
        if (t2 < NT / 2 - 1) {
            STAGE(0)                              // stage K-tile 2*t2+2 into freed buf0
            asm volatile("s_waitcnt vmcnt(8)" ::: "memory");  // K-tile 2*t2+1 landed
        } else {
            asm volatile("s_waitcnt vmcnt(0)" ::: "memory");  // final: drain for last tile
        }
        __builtin_amdgcn_s_barrier();
        KTILE(1)                                  // compute K-tile 2*t2+1
        if (t2 < NT / 2 - 1) {
            STAGE(1)                              // stage K-tile 2*t2+3 into freed buf1
            asm volatile("s_waitcnt vmcnt(8)" ::: "memory");  // K-tile 2*t2+2 landed
            __builtin_amdgcn_s_barrier();
        }
    }

#undef KTILE
#undef PH
#undef STAGE

    // epilogue: raw partials (C/D layout: col = lane&15, row = q*4 + r)
    float* pbase = part + (size_t)sp * DIM_M * DIM_N;
    #pragma unroll
    for (int ni = 0; ni < 4; ++ni) {
        const int col = n0 + wn * 64 + ni * 16 + (lane & 15);
        #pragma unroll
        for (int mi = 0; mi < 8; ++mi) {
            const int row = m0 + wrm * 128 + mi * 16 + (q << 2);
            #pragma unroll
            for (int r = 0; r < 4; ++r)
                pbase[(size_t)(row + r) * DIM_N + col] = acc[mi][ni][r];
        }
    }
}

// out = tanh(sum_splits(part) + bias), vectorized float4
__global__ void reduce_tanh(const floatx4* __restrict__ part, const float* __restrict__ bias,
                            floatx4* __restrict__ out) {
    const int n4 = DIM_M * DIM_N / 4;
    int i = blockIdx.x * blockDim.x + threadIdx.x;
    if (i < n4) {
        floatx4 s = part[i];
        #pragma unroll
        for (int sp = 1; sp < SPLIT; ++sp)
            s += part[(size_t)sp * n4 + i];
        floatx4 b = ((const floatx4*)bias)[i & (DIM_N / 4 - 1)];
        floatx4 o;
        o.x = tanhf(s.x + b.x);
        o.y = tanhf(s.y + b.y);
        o.z = tanhf(s.z + b.z);
        o.w = tanhf(s.w + b.w);
        out[i] = o;
    }
}

extern "C" void kernel_launch(void* const* d_in, const int* in_sizes, int n_in,
                              void* d_out, int out_size, void* d_ws, size_t ws_size,
                              hipStream_t stream) {
    const float* x    = (const float*)d_in[0];
    const float* kv   = (const float*)d_in[1];
    const float* bias = (const float*)d_in[2];
    const int*   ind  = (const int*)d_in[3];
    float* out = (float*)d_out;
    const int nnz = in_sizes[1];

    char* ws = (char*)d_ws;
    _Float16* wh = (_Float16*)ws;                               // [N][K] fp16, 64 MB
    const size_t whBytes = (size_t)DIM_N * DIM_K * 2;
    _Float16* xh = (_Float16*)(ws + whBytes);                   // [M][K] fp16, 16 MB
    const size_t xhBytes = (size_t)DIM_M * DIM_K * 2;
    float* part = (float*)(ws + whBytes + xhBytes);             // [SPLIT][M][N] fp32, 64 MB

    const int wN4h = (int)(whBytes / 16);               // fp16 W zero-fill, 16B units
    const int xN4  = (int)((size_t)DIM_M * DIM_K / 4);  // x float4 count
    const int oN4  = DIM_M * DIM_N / 4;

    zero_f4<<<(wN4h + 255) / 256, 256, 0, stream>>>((floatx4*)wh, wN4h);
    cvt_f2h<<<(xN4 + 255) / 256, 256, 0, stream>>>((const floatx4*)x, (Half4*)xh, xN4);
    const int nq = (nnz + 3) / 4;
    scatter_h<<<(nq + 255) / 256, 256, 0, stream>>>(ind, kv, wh, nnz);

    hipFuncSetAttribute((const void*)gemm8_k,
                        hipFuncAttributeMaxDynamicSharedMemorySize, 131072);
    gemm8_k<<<dim3(256), 512, 131072, stream>>>(xh, wh, part);

    reduce_tanh<<<(oN4 + 255) / 256, 256, 0, stream>>>((const floatx4*)part, bias, (floatx4*)out);
}

// Round 5
// 188.682 us; speedup vs baseline: 1.0223x; 1.0223x over previous
//
#include <hip/hip_runtime.h>
#include <hip/hip_fp16.h>
#include <cmath>

#define DIM_M 1024   // B (batch)
#define DIM_K 8192   // D
#define DIM_N 4096   // U
#define SPLIT 4
#define KSPL  (DIM_K / SPLIT)   // 2048
#define BKT   64
#define NT    (KSPL / BKT)      // 32 K-tiles per block
#define NB    1024              // scatter bins (4 u-rows = 128 KB fp32 region each)
#define EPB   2048              // entries per block in hist/reorder

typedef __attribute__((ext_vector_type(8))) _Float16 half8;
typedef __attribute__((ext_vector_type(4))) float floatx4;

struct __align__(8) Half4 { __half2 a, b; };

__device__ inline void gload_lds16(const void* g, void* l) {
    __builtin_amdgcn_global_load_lds(
        (const __attribute__((address_space(1))) void*)g,
        (__attribute__((address_space(3))) void*)l, 16, 0, 0);
}

__global__ void cvt_f2h(const floatx4* __restrict__ in, Half4* __restrict__ out, int n4) {
    int i = blockIdx.x * blockDim.x + threadIdx.x;
    if (i < n4) {
        floatx4 f = in[i];
        Half4 h;
        h.a = __floats2half2_rn(f.x, f.y);
        h.b = __floats2half2_rn(f.z, f.w);
        out[i] = h;
    }
}

// ---- scatter pipeline: bin -> scan -> reorder -> LDS accumulate ------------

// K1: per-block histogram over NB bins (bin = u>>2)
__global__ void hist_k(const int* __restrict__ ind, unsigned* __restrict__ cnt, int nnz) {
    __shared__ unsigned h[NB];
    const int tid = threadIdx.x;
    for (int i = tid; i < NB; i += 256) h[i] = 0u;
    __syncthreads();
    const int base = blockIdx.x * EPB;
    const int lim = min(nnz - base, EPB);
    for (int k = tid; k < lim; k += 256) {
        int u = ind[2 * (size_t)(base + k) + 1];
        atomicAdd(&h[u >> 2], 1u);
    }
    __syncthreads();
    for (int i = tid; i < NB; i += 256) cnt[(size_t)blockIdx.x * NB + i] = h[i];
}

// K2a: per-bin exclusive scan over blocks, in place on cnt; bin totals -> bb[bin]
__global__ void scanb_k(unsigned* cnt, unsigned* __restrict__ bb, int nblk) {
    __shared__ unsigned s[256];
    const int tid = threadIdx.x, bin = blockIdx.x;
    unsigned carry = 0;
    for (int c0 = 0; c0 < nblk; c0 += 256) {
        int b = c0 + tid;
        unsigned v = (b < nblk) ? cnt[(size_t)b * NB + bin] : 0u;
        s[tid] = v;
        __syncthreads();
        for (int off = 1; off < 256; off <<= 1) {
            unsigned add = (tid >= off) ? s[tid - off] : 0u;
            __syncthreads();
            s[tid] += add;
            __syncthreads();
        }
        if (b < nblk) cnt[(size_t)b * NB + bin] = carry + s[tid] - v;
        carry += s[255];
        __syncthreads();
    }
    if (tid == 0) bb[bin] = carry;
}

// K2b: exclusive scan of bin totals (single block, NB threads), bb[NB] = total
__global__ void scant_k(unsigned* bb) {
    __shared__ unsigned s[NB];
    const int tid = threadIdx.x;
    unsigned v = bb[tid];
    s[tid] = v;
    __syncthreads();
    for (int off = 1; off < NB; off <<= 1) {
        unsigned add = (tid >= off) ? s[tid - off] : 0u;
        __syncthreads();
        s[tid] += add;
        __syncthreads();
    }
    bb[tid] = s[tid] - v;
    if (tid == NB - 1) bb[NB] = s[tid];
}

// K3: write each entry to its unique slot (binBase + blockStart + localRank)
__global__ void reorder_k(const int* __restrict__ ind, const float* __restrict__ kv,
                          const unsigned* __restrict__ start, const unsigned* __restrict__ bb,
                          uint2* __restrict__ ebuf, int nnz) {
    __shared__ unsigned cur[NB];
    const int tid = threadIdx.x;
    for (int i = tid; i < NB; i += 256) cur[i] = 0u;
    __syncthreads();
    const int base = blockIdx.x * EPB;
    const int lim = min(nnz - base, EPB);
    for (int k = tid; k < lim; k += 256) {
        size_t e = (size_t)base + k;
        int d = ind[2 * e];
        int u = ind[2 * e + 1];
        float v = kv[e];
        int bin = u >> 2;
        unsigned r = atomicAdd(&cur[bin], 1u);
        unsigned pos = bb[bin] + start[(size_t)blockIdx.x * NB + bin] + r;
        unsigned lidx = ((unsigned)(u & 3) << 13) | (unsigned)d;   // local idx in 4x8192 region
        ebuf[pos] = make_uint2(lidx, __float_as_uint(v));
    }
}

// K4: per-bin LDS fp32 accumulate + dense fp16 writeout (replaces zero-fill too)
__global__ __launch_bounds__(256) void accum_k(const uint2* __restrict__ ebuf,
                                               const unsigned* __restrict__ bb,
                                               Half4* __restrict__ wh4) {
    extern __shared__ float reg[];            // 32768 floats = 128 KB
    floatx4* reg4 = (floatx4*)reg;
    const int tid = threadIdx.x, bin = blockIdx.x;
    for (int i = tid; i < 8192; i += 256) reg4[i] = floatx4{0.f, 0.f, 0.f, 0.f};
    __syncthreads();
    const unsigned s0 = bb[bin], s1 = bb[bin + 1];
    for (unsigned e = s0 + tid; e < s1; e += 256) {
        uint2 p = ebuf[e];
        atomicAdd(&reg[p.x], __uint_as_float(p.y));   // ds_add_f32
    }
    __syncthreads();
    for (int i = tid; i < 8192; i += 256) {
        floatx4 f = reg4[i];
        Half4 h;
        h.a = __floats2half2_rn(f.x, f.y);
        h.b = __floats2half2_rn(f.z, f.w);
        wh4[(size_t)bin * 8192 + i] = h;
    }
}

// ---------------------------------------------------------------------------
// 256x256 8-phase split-K GEMM: part[split][M][N] = A[M][ksl] * B^T[N][ksl]
// (unchanged from R2/R3)
// ---------------------------------------------------------------------------
__global__ __launch_bounds__(512, 2) void gemm8_k(
    const _Float16* __restrict__ Ah,   // [M][K] fp16
    const _Float16* __restrict__ Bh,   // [N][K] fp16
    float*          __restrict__ part) // [SPLIT][M][N] fp32
{
    extern __shared__ char smem[];

    const int tid  = threadIdx.x;
    const int lane = tid & 63;
    const int wave = tid >> 6;

    const int bid = blockIdx.x;
    const int swz = (bid & 7) * 32 + (bid >> 3);
    const int n0  = (swz >> 4) * 256;
    const int rem = swz & 15;
    const int m0  = (rem >> 2) * 256;
    const int sp  = rem & 3;
    const size_t kbase = (size_t)sp * KSPL;

    const int srow = tid >> 3;
    const int sch  = (tid & 7) ^ (srow & 7);
    const _Float16* aSg = Ah + (size_t)(m0 + srow) * DIM_K + kbase + sch * 8;
    const _Float16* bSg = Bh + (size_t)(n0 + srow) * DIM_K + kbase + sch * 8;
    char* aLg = smem + wave * 1024;
    char* bLg = smem + 32768 + wave * 1024;

    const int wn  = wave & 3;
    const int wrm = wave >> 2;
    const int q   = lane >> 4;
    const int l7  = lane & 7;
    const char* aRd = smem + (wrm * 128 + (lane & 15)) * 128;
    const char* bRd = smem + 32768 + (wn * 64 + (lane & 15)) * 128;
    const int ch0 = ((0 * 4 + q) ^ l7) * 16;
    const int ch1 = ((1 * 4 + q) ^ l7) * 16;

    floatx4 acc[8][4] = {};
    half8 aF[4], bF[4];

#define STAGE(C)                                                              \
    { _Pragma("unroll") for (int j = 0; j < 4; ++j) {                         \
        gload_lds16(aSg + (size_t)j * (64 * DIM_K), aLg + (C) * 65536 + j * 8192); \
        gload_lds16(bSg + (size_t)j * (64 * DIM_K), bLg + (C) * 65536 + j * 8192); } \
      aSg += BKT; bSg += BKT; }

#define PH(C, MIOFF, CH, RB)                                                  \
    { _Pragma("unroll") for (int i = 0; i < 4; ++i)                           \
        aF[i] = *(const half8*)(aRd + (C) * 65536 + ((MIOFF) + i) * 2048 + (CH)); \
      if (RB) { _Pragma("unroll") for (int i = 0; i < 4; ++i)                 \
        bF[i] = *(const half8*)(bRd + (C) * 65536 + i * 2048 + (CH)); }       \
      __builtin_amdgcn_s_barrier();                                           \
      asm volatile("s_waitcnt lgkmcnt(0)" ::: "memory");                      \
      __builtin_amdgcn_sched_barrier(0);                                      \
      __builtin_amdgcn_s_setprio(1);                                          \
      _Pragma("unroll") for (int mi = 0; mi < 4; ++mi)                        \
        _Pragma("unroll") for (int ni = 0; ni < 4; ++ni)                      \
          acc[(MIOFF) + mi][ni] = __builtin_amdgcn_mfma_f32_16x16x32_f16(     \
              aF[mi], bF[ni], acc[(MIOFF) + mi][ni], 0, 0, 0);                \
      __builtin_amdgcn_s_setprio(0);                                          \
      __builtin_amdgcn_s_barrier(); }

#define KTILE(C) PH(C, 0, ch0, 1) PH(C, 4, ch0, 0) PH(C, 0, ch1, 1) PH(C, 4, ch1, 0)

    STAGE(0)
    STAGE(1)
    asm volatile("s_waitcnt vmcnt(8)" ::: "memory");
    __builtin_amdgcn_s_barrier();

    for (int t2 = 0; t2 < NT / 2; ++t2) {
        KTILE(0)
        if (t2 < NT / 2 - 1) {
            STAGE(0)
            asm volatile("s_waitcnt vmcnt(8)" ::: "memory");
        } else {
            asm volatile("s_waitcnt vmcnt(0)" ::: "memory");
        }
        __builtin_amdgcn_s_barrier();
        KTILE(1)
        if (t2 < NT / 2 - 1) {
            STAGE(1)
            asm volatile("s_waitcnt vmcnt(8)" ::: "memory");
            __builtin_amdgcn_s_barrier();
        }
    }

#undef KTILE
#undef PH
#undef STAGE

    float* pbase = part + (size_t)sp * DIM_M * DIM_N;
    #pragma unroll
    for (int ni = 0; ni < 4; ++ni) {
        const int col = n0 + wn * 64 + ni * 16 + (lane & 15);
        #pragma unroll
        for (int mi = 0; mi < 8; ++mi) {
            const int row = m0 + wrm * 128 + mi * 16 + (q << 2);
            #pragma unroll
            for (int r = 0; r < 4; ++r)
                pbase[(size_t)(row + r) * DIM_N + col] = acc[mi][ni][r];
        }
    }
}

// out = tanh(sum_splits(part) + bias), vectorized float4
__global__ void reduce_tanh(const floatx4* __restrict__ part, const float* __restrict__ bias,
                            floatx4* __restrict__ out) {
    const int n4 = DIM_M * DIM_N / 4;
    int i = blockIdx.x * blockDim.x + threadIdx.x;
    if (i < n4) {
        floatx4 s = part[i];
        #pragma unroll
        for (int sp = 1; sp < SPLIT; ++sp)
            s += part[(size_t)sp * n4 + i];
        floatx4 b = ((const floatx4*)bias)[i & (DIM_N / 4 - 1)];
        floatx4 o;
        o.x = tanhf(s.x + b.x);
        o.y = tanhf(s.y + b.y);
        o.z = tanhf(s.z + b.z);
        o.w = tanhf(s.w + b.w);
        out[i] = o;
    }
}

extern "C" void kernel_launch(void* const* d_in, const int* in_sizes, int n_in,
                              void* d_out, int out_size, void* d_ws, size_t ws_size,
                              hipStream_t stream) {
    const float* x    = (const float*)d_in[0];
    const float* kv   = (const float*)d_in[1];
    const float* bias = (const float*)d_in[2];
    const int*   ind  = (const int*)d_in[3];
    float* out = (float*)d_out;
    const int nnz = in_sizes[1];

    char* ws = (char*)d_ws;
    _Float16* wh = (_Float16*)ws;                               // [N][K] fp16, 64 MB
    const size_t whBytes = (size_t)DIM_N * DIM_K * 2;
    _Float16* xh = (_Float16*)(ws + whBytes);                   // [M][K] fp16, 16 MB
    const size_t xhBytes = (size_t)DIM_M * DIM_K * 2;
    float* part = (float*)(ws + whBytes + xhBytes);             // [SPLIT][M][N] fp32, 64 MB
    const size_t partBytes = (size_t)SPLIT * DIM_M * DIM_N * 4;
    uint2* ebuf = (uint2*)(ws + whBytes + xhBytes + partBytes); // nnz*8 B (<=16 MB)
    const size_t ebufBytes = (size_t)16 << 20;
    unsigned* cnt = (unsigned*)(ws + whBytes + xhBytes + partBytes + ebufBytes); // 4 MB
    const size_t cntBytes = (size_t)1024 * NB * 4;
    unsigned* bb = (unsigned*)(ws + whBytes + xhBytes + partBytes + ebufBytes + cntBytes); // NB+1

    const int xN4 = (int)((size_t)DIM_M * DIM_K / 4);
    const int oN4 = DIM_M * DIM_N / 4;
    const int nblk = (nnz + EPB - 1) / EPB;

    cvt_f2h<<<(xN4 + 255) / 256, 256, 0, stream>>>((const floatx4*)x, (Half4*)xh, xN4);
    hist_k<<<nblk, 256, 0, stream>>>(ind, cnt, nnz);
    scanb_k<<<NB, 256, 0, stream>>>(cnt, bb, nblk);
    scant_k<<<1, NB, 0, stream>>>(bb);
    reorder_k<<<nblk, 256, 0, stream>>>(ind, kv, cnt, bb, ebuf, nnz);

    hipFuncSetAttribute((const void*)accum_k,
                        hipFuncAttributeMaxDynamicSharedMemorySize, 131072);
    accum_k<<<NB, 256, 131072, stream>>>(ebuf, bb, (Half4*)wh);

    hipFuncSetAttribute((const void*)gemm8_k,
                        hipFuncAttributeMaxDynamicSharedMemorySize, 131072);
    gemm8_k<<<dim3(256), 512, 131072, stream>>>(xh, wh, part);

    reduce_tanh<<<(oN4 + 255) / 256, 256, 0, stream>>>((const floatx4*)part, bias, (floatx4*)out);
}

// Round 6
// 141.694 us; speedup vs baseline: 1.3614x; 1.3316x over previous
//
#include <hip/hip_runtime.h>
#include <hip/hip_fp16.h>
#include <cmath>

#define DIM_M 1024   // B (batch)
#define DIM_K 8192   // D
#define DIM_N 4096   // U
#define SPLIT 4
#define KSPL  (DIM_K / SPLIT)   // 2048
#define BKT   64
#define NT    (KSPL / BKT)      // 32 K-tiles per block
#define NB    1024              // scatter bins (4 u-rows = 128 KB fp32 region each)
#define EPB   8192              // entries per block in hist/reorder

typedef __attribute__((ext_vector_type(8))) _Float16 half8;
typedef __attribute__((ext_vector_type(4))) float floatx4;

struct __align__(8) Half4 { __half2 a, b; };

__device__ inline void gload_lds16(const void* g, void* l) {
    __builtin_amdgcn_global_load_lds(
        (const __attribute__((address_space(1))) void*)g,
        (__attribute__((address_space(3))) void*)l, 16, 0, 0);
}

__global__ void cvt_f2h(const floatx4* __restrict__ in, Half4* __restrict__ out, int n4) {
    int i = blockIdx.x * blockDim.x + threadIdx.x;
    if (i < n4) {
        floatx4 f = in[i];
        Half4 h;
        h.a = __floats2half2_rn(f.x, f.y);
        h.b = __floats2half2_rn(f.z, f.w);
        out[i] = h;
    }
}

// ---- scatter pipeline: bin -> scan -> reorder(LDS-clustered) -> accumulate --

// K1: per-block histogram over NB bins (bin = u>>2), int4-vectorized
__global__ __launch_bounds__(512) void hist_k(const int* __restrict__ ind,
                                              unsigned* __restrict__ cnt, int nnz) {
    __shared__ unsigned h[NB];
    const int tid = threadIdx.x;
    for (int i = tid; i < NB; i += 512) h[i] = 0u;
    __syncthreads();
    const int base = blockIdx.x * EPB;
    const int lim = min(nnz - base, EPB);
    const int4* ip = (const int4*)(ind + 2 * (size_t)base);
    for (int k2 = tid; k2 < lim / 2; k2 += 512) {
        int4 w = ip[k2];
        atomicAdd(&h[w.y >> 2], 1u);
        atomicAdd(&h[w.w >> 2], 1u);
    }
    if ((lim & 1) && tid == 0) {
        int u = ind[2 * (size_t)(base + lim - 1) + 1];
        atomicAdd(&h[u >> 2], 1u);
    }
    __syncthreads();
    for (int i = tid; i < NB; i += 512) cnt[(size_t)blockIdx.x * NB + i] = h[i];
}

// K2a: per-bin exclusive scan over blocks, in place on cnt; bin totals -> bb[bin]
__global__ void scanb_k(unsigned* cnt, unsigned* __restrict__ bb, int nblk) {
    __shared__ unsigned s[256];
    const int tid = threadIdx.x, bin = blockIdx.x;
    unsigned carry = 0;
    for (int c0 = 0; c0 < nblk; c0 += 256) {
        int b = c0 + tid;
        unsigned v = (b < nblk) ? cnt[(size_t)b * NB + bin] : 0u;
        s[tid] = v;
        __syncthreads();
        for (int off = 1; off < 256; off <<= 1) {
            unsigned add = (tid >= off) ? s[tid - off] : 0u;
            __syncthreads();
            s[tid] += add;
            __syncthreads();
        }
        if (b < nblk) cnt[(size_t)b * NB + bin] = carry + s[tid] - v;
        carry += s[255];
        __syncthreads();
    }
    if (tid == 0) bb[bin] = carry;
}

// K2b: exclusive scan of bin totals (single block, NB threads), bb[NB] = total
__global__ void scant_k(unsigned* bb) {
    __shared__ unsigned s[NB];
    const int tid = threadIdx.x;
    unsigned v = bb[tid];
    s[tid] = v;
    __syncthreads();
    for (int off = 1; off < NB; off <<= 1) {
        unsigned add = (tid >= off) ? s[tid - off] : 0u;
        __syncthreads();
        s[tid] += add;
        __syncthreads();
    }
    bb[tid] = s[tid] - v;
    if (tid == NB - 1) bb[NB] = s[tid];
}

// K3: LDS-clustered reorder — local hist+scan, scatter into LDS by bin,
// then run-coalesced writeout (avg 8-entry = 64B contiguous segments).
__global__ __launch_bounds__(512) void reorder_k(const int* __restrict__ ind,
                                                 const float* __restrict__ kv,
                                                 const unsigned* __restrict__ start,
                                                 const unsigned* __restrict__ bb,
                                                 uint2* __restrict__ ebuf, int nnz) {
    extern __shared__ char rsm[];
    uint2*    buf  = (uint2*)rsm;                 // 64 KB  entries clustered by bin
    unsigned* gofs = (unsigned*)(rsm + 65536);    // 32 KB  per-slot global position
    unsigned* cur  = (unsigned*)(rsm + 98304);    //  4 KB  hist -> cursor
    unsigned* dl   = (unsigned*)(rsm + 102400);   //  4 KB  global delta per bin
    unsigned* ss   = (unsigned*)(rsm + 106496);   //  2 KB  512 pair-sums for scan
    const int tid = threadIdx.x, blk = blockIdx.x;
    const int base = blk * EPB;
    const int lim = min(nnz - base, EPB);
    const int4*   ip = (const int4*)(ind + 2 * (size_t)base);
    const float2* vp = (const float2*)(kv + base);

    // 1) local hist
    for (int i = tid; i < NB; i += 512) cur[i] = 0u;
    __syncthreads();
    for (int k2 = tid; k2 < lim / 2; k2 += 512) {
        int4 w = ip[k2];
        atomicAdd(&cur[w.y >> 2], 1u);
        atomicAdd(&cur[w.w >> 2], 1u);
    }
    if ((lim & 1) && tid == 0) {
        int u = ind[2 * (size_t)(base + lim - 1) + 1];
        atomicAdd(&cur[u >> 2], 1u);
    }
    __syncthreads();
    // 2) exclusive scan over 1024 bins (2 bins/thread)
    unsigned c0 = cur[2 * tid], c1 = cur[2 * tid + 1];
    unsigned own = c0 + c1;
    ss[tid] = own;
    __syncthreads();
    for (int off = 1; off < 512; off <<= 1) {
        unsigned t = (tid >= off) ? ss[tid - off] : 0u;
        __syncthreads();
        ss[tid] += t;
        __syncthreads();
    }
    unsigned e0 = ss[tid] - own;
    unsigned e1 = e0 + c0;
    __syncthreads();
    cur[2 * tid]     = e0;
    cur[2 * tid + 1] = e1;
    unsigned g0 = bb[2 * tid]     + start[(size_t)blk * NB + 2 * tid];
    unsigned g1 = bb[2 * tid + 1] + start[(size_t)blk * NB + 2 * tid + 1];
    dl[2 * tid]     = g0 - e0;
    dl[2 * tid + 1] = g1 - e1;
    __syncthreads();
    // 3) scatter into LDS (random LDS, cheap)
    for (int k2 = tid; k2 < lim / 2; k2 += 512) {
        int4 w = ip[k2];
        float2 v = vp[k2];
        int b0 = w.y >> 2, b1 = w.w >> 2;
        unsigned r0 = atomicAdd(&cur[b0], 1u);
        buf[r0]  = make_uint2(((unsigned)(w.y & 3) << 13) | (unsigned)w.x, __float_as_uint(v.x));
        gofs[r0] = dl[b0] + r0;
        unsigned r1 = atomicAdd(&cur[b1], 1u);
        buf[r1]  = make_uint2(((unsigned)(w.w & 3) << 13) | (unsigned)w.z, __float_as_uint(v.y));
        gofs[r1] = dl[b1] + r1;
    }
    if ((lim & 1) && tid == 0) {
        size_t e = (size_t)base + lim - 1;
        int d = ind[2 * e], u = ind[2 * e + 1];
        int b = u >> 2;
        unsigned r = atomicAdd(&cur[b], 1u);
        buf[r]  = make_uint2(((unsigned)(u & 3) << 13) | (unsigned)d, __float_as_uint(kv[e]));
        gofs[r] = dl[b] + r;
    }
    __syncthreads();
    // 4) run-coalesced writeout
    for (int j = tid; j < lim; j += 512)
        ebuf[gofs[j]] = buf[j];
}

// K4: per-bin LDS fp32 accumulate + dense fp16 writeout (replaces zero-fill too)
__global__ __launch_bounds__(512) void accum_k(const uint2* __restrict__ ebuf,
                                               const unsigned* __restrict__ bb,
                                               Half4* __restrict__ wh4) {
    extern __shared__ float reg[];            // 32768 floats = 128 KB
    floatx4* reg4 = (floatx4*)reg;
    const int tid = threadIdx.x, bin = blockIdx.x;
    for (int i = tid; i < 8192; i += 512) reg4[i] = floatx4{0.f, 0.f, 0.f, 0.f};
    __syncthreads();
    const unsigned s0 = bb[bin], s1 = bb[bin + 1];
    for (unsigned e = s0 + tid; e < s1; e += 512) {
        uint2 p = ebuf[e];
        atomicAdd(&reg[p.x], __uint_as_float(p.y));   // ds_add_f32
    }
    __syncthreads();
    for (int i = tid; i < 8192; i += 512) {
        floatx4 f = reg4[i];
        Half4 h;
        h.a = __floats2half2_rn(f.x, f.y);
        h.b = __floats2half2_rn(f.z, f.w);
        wh4[(size_t)bin * 8192 + i] = h;
    }
}

// ---------------------------------------------------------------------------
// 256x256 split-K GEMM, free-running waves: per K-tile = 2 chunks of
// {12 ds_read -> lgkmcnt(0) -> 32 MFMA}, only 2 barriers per K-tile
// (pre-STAGE overwrite hazard + tile-landed). Raw s_barrier only — never
// __syncthreads (it drains vmcnt(0) and kills the in-flight prefetch).
// ---------------------------------------------------------------------------
__global__ __launch_bounds__(512, 2) void gemm8_k(
    const _Float16* __restrict__ Ah,   // [M][K] fp16
    const _Float16* __restrict__ Bh,   // [N][K] fp16
    float*          __restrict__ part) // [SPLIT][M][N] fp32
{
    extern __shared__ char smem[];

    const int tid  = threadIdx.x;
    const int lane = tid & 63;
    const int wave = tid >> 6;

    const int bid = blockIdx.x;
    const int swz = (bid & 7) * 32 + (bid >> 3);
    const int n0  = (swz >> 4) * 256;
    const int rem = swz & 15;
    const int m0  = (rem >> 2) * 256;
    const int sp  = rem & 3;
    const size_t kbase = (size_t)sp * KSPL;

    const int srow = tid >> 3;
    const int sch  = (tid & 7) ^ (srow & 7);
    const _Float16* aSg = Ah + (size_t)(m0 + srow) * DIM_K + kbase + sch * 8;
    const _Float16* bSg = Bh + (size_t)(n0 + srow) * DIM_K + kbase + sch * 8;
    char* aLg = smem + wave * 1024;
    char* bLg = smem + 32768 + wave * 1024;

    const int wn  = wave & 3;
    const int wrm = wave >> 2;
    const int q   = lane >> 4;
    const int l7  = lane & 7;
    const char* aRd = smem + (wrm * 128 + (lane & 15)) * 128;
    const char* bRd = smem + 32768 + (wn * 64 + (lane & 15)) * 128;
    const int ch0 = ((0 * 4 + q) ^ l7) * 16;
    const int ch1 = ((1 * 4 + q) ^ l7) * 16;

    floatx4 acc[8][4] = {};
    half8 aF[8], bF[4];

#define STAGE(C)                                                              \
    { _Pragma("unroll") for (int j = 0; j < 4; ++j) {                         \
        gload_lds16(aSg + (size_t)j * (64 * DIM_K), aLg + (C) * 65536 + j * 8192); \
        gload_lds16(bSg + (size_t)j * (64 * DIM_K), bLg + (C) * 65536 + j * 8192); } \
      aSg += BKT; bSg += BKT; }

#define CHUNK(C, CH)                                                          \
    { _Pragma("unroll") for (int i = 0; i < 8; ++i)                           \
        aF[i] = *(const half8*)(aRd + (C) * 65536 + i * 2048 + (CH));         \
      _Pragma("unroll") for (int i = 0; i < 4; ++i)                           \
        bF[i] = *(const half8*)(bRd + (C) * 65536 + i * 2048 + (CH));         \
      asm volatile("s_waitcnt lgkmcnt(0)" ::: "memory");                      \
      __builtin_amdgcn_sched_barrier(0);                                      \
      __builtin_amdgcn_s_setprio(1);                                          \
      _Pragma("unroll") for (int mi = 0; mi < 8; ++mi)                        \
        _Pragma("unroll") for (int ni = 0; ni < 4; ++ni)                      \
          acc[mi][ni] = __builtin_amdgcn_mfma_f32_16x16x32_f16(               \
              aF[mi], bF[ni], acc[mi][ni], 0, 0, 0);                          \
      __builtin_amdgcn_s_setprio(0); }

#define KTILE(C) CHUNK(C, ch0) CHUNK(C, ch1)

    // prologue: stage K-tiles 0,1; wait tile 0 (8 newest may stay in flight)
    STAGE(0)
    STAGE(1)
    asm volatile("s_waitcnt vmcnt(8)" ::: "memory");
    __builtin_amdgcn_s_barrier();

    for (int t2 = 0; t2 < NT / 2; ++t2) {
        KTILE(0)                                  // compute tile 2*t2 (buf0)
        __builtin_amdgcn_s_barrier();             // all waves done reading buf0
        if (t2 < NT / 2 - 1) {
            STAGE(0)                              // stage tile 2*t2+2 into buf0
            asm volatile("s_waitcnt vmcnt(8)" ::: "memory");  // tile 2*t2+1 landed
        } else {
            asm volatile("s_waitcnt vmcnt(0)" ::: "memory");  // last tile landed
        }
        __builtin_amdgcn_s_barrier();
        KTILE(1)                                  // compute tile 2*t2+1 (buf1)
        if (t2 < NT / 2 - 1) {
            __builtin_amdgcn_s_barrier();         // all waves done reading buf1
            STAGE(1)                              // stage tile 2*t2+3 into buf1
            asm volatile("s_waitcnt vmcnt(8)" ::: "memory");  // tile 2*t2+2 landed
            __builtin_amdgcn_s_barrier();
        }
    }

#undef KTILE
#undef CHUNK
#undef STAGE

    // epilogue: raw partials (C/D layout: col = lane&15, row = q*4 + r)
    float* pbase = part + (size_t)sp * DIM_M * DIM_N;
    #pragma unroll
    for (int ni = 0; ni < 4; ++ni) {
        const int col = n0 + wn * 64 + ni * 16 + (lane & 15);
        #pragma unroll
        for (int mi = 0; mi < 8; ++mi) {
            const int row = m0 + wrm * 128 + mi * 16 + (q << 2);
            #pragma unroll
            for (int r = 0; r < 4; ++r)
                pbase[(size_t)(row + r) * DIM_N + col] = acc[mi][ni][r];
        }
    }
}

// out = tanh(sum_splits(part) + bias), vectorized float4
__global__ void reduce_tanh(const floatx4* __restrict__ part, const float* __restrict__ bias,
                            floatx4* __restrict__ out) {
    const int n4 = DIM_M * DIM_N / 4;
    int i = blockIdx.x * blockDim.x + threadIdx.x;
    if (i < n4) {
        floatx4 s = part[i];
        #pragma unroll
        for (int sp = 1; sp < SPLIT; ++sp)
            s += part[(size_t)sp * n4 + i];
        floatx4 b = ((const floatx4*)bias)[i & (DIM_N / 4 - 1)];
        floatx4 o;
        o.x = tanhf(s.x + b.x);
        o.y = tanhf(s.y + b.y);
        o.z = tanhf(s.z + b.z);
        o.w = tanhf(s.w + b.w);
        out[i] = o;
    }
}

extern "C" void kernel_launch(void* const* d_in, const int* in_sizes, int n_in,
                              void* d_out, int out_size, void* d_ws, size_t ws_size,
                              hipStream_t stream) {
    const float* x    = (const float*)d_in[0];
    const float* kv   = (const float*)d_in[1];
    const float* bias = (const float*)d_in[2];
    const int*   ind  = (const int*)d_in[3];
    float* out = (float*)d_out;
    const int nnz = in_sizes[1];

    char* ws = (char*)d_ws;
    _Float16* wh = (_Float16*)ws;                               // [N][K] fp16, 64 MB
    const size_t whBytes = (size_t)DIM_N * DIM_K * 2;
    _Float16* xh = (_Float16*)(ws + whBytes);                   // [M][K] fp16, 16 MB
    const size_t xhBytes = (size_t)DIM_M * DIM_K * 2;
    float* part = (float*)(ws + whBytes + xhBytes);             // [SPLIT][M][N] fp32, 64 MB
    const size_t partBytes = (size_t)SPLIT * DIM_M * DIM_N * 4;
    uint2* ebuf = (uint2*)(ws + whBytes + xhBytes + partBytes); // nnz*8 B (<=16 MB)
    const size_t ebufBytes = (size_t)16 << 20;
    unsigned* cnt = (unsigned*)(ws + whBytes + xhBytes + partBytes + ebufBytes); // 4 MB
    const size_t cntBytes = (size_t)1024 * NB * 4;
    unsigned* bb = (unsigned*)(ws + whBytes + xhBytes + partBytes + ebufBytes + cntBytes); // NB+1

    const int xN4 = (int)((size_t)DIM_M * DIM_K / 4);
    const int oN4 = DIM_M * DIM_N / 4;
    const int nblk = (nnz + EPB - 1) / EPB;

    cvt_f2h<<<(xN4 + 255) / 256, 256, 0, stream>>>((const floatx4*)x, (Half4*)xh, xN4);
    hist_k<<<nblk, 512, 0, stream>>>(ind, cnt, nnz);
    scanb_k<<<NB, 256, 0, stream>>>(cnt, bb, nblk);
    scant_k<<<1, NB, 0, stream>>>(bb);

    hipFuncSetAttribute((const void*)reorder_k,
                        hipFuncAttributeMaxDynamicSharedMemorySize, 131072);
    reorder_k<<<nblk, 512, 110592, stream>>>(ind, kv, cnt, bb, ebuf, nnz);

    hipFuncSetAttribute((const void*)accum_k,
                        hipFuncAttributeMaxDynamicSharedMemorySize, 131072);
    accum_k<<<NB, 512, 131072, stream>>>(ebuf, bb, (Half4*)wh);

    hipFuncSetAttribute((const void*)gemm8_k,
                        hipFuncAttributeMaxDynamicSharedMemorySize, 131072);
    gemm8_k<<<dim3(256), 512, 131072, stream>>>(xh, wh, part);

    reduce_tanh<<<(oN4 + 255) / 256, 256, 0, stream>>>((const floatx4*)part, bias, (floatx4*)out);
}

// Round 7
// 140.216 us; speedup vs baseline: 1.3757x; 1.0105x over previous
//
#include <hip/hip_runtime.h>
#include <hip/hip_fp16.h>
#include <cmath>

#define DIM_M 1024   // B (batch)
#define DIM_K 8192   // D
#define DIM_N 4096   // U
#define SPLIT 4
#define KSPL  (DIM_K / SPLIT)   // 2048
#define BKT   64
#define NT    (KSPL / BKT)      // 32 K-tiles per block
#define NB    1024              // scatter bins (4 u-rows = 128 KB fp32 region each)
#define EPB   8192              // entries per block in hist/reorder

typedef __attribute__((ext_vector_type(8))) _Float16 half8;
typedef __attribute__((ext_vector_type(4))) float floatx4;

struct __align__(8) Half4 { __half2 a, b; };

__device__ inline void gload_lds16(const void* g, void* l) {
    __builtin_amdgcn_global_load_lds(
        (const __attribute__((address_space(1))) void*)g,
        (__attribute__((address_space(3))) void*)l, 16, 0, 0);
}

__global__ void cvt_f2h(const floatx4* __restrict__ in, Half4* __restrict__ out, int n4) {
    int i = blockIdx.x * blockDim.x + threadIdx.x;
    if (i < n4) {
        floatx4 f = in[i];
        Half4 h;
        h.a = __floats2half2_rn(f.x, f.y);
        h.b = __floats2half2_rn(f.z, f.w);
        out[i] = h;
    }
}

// ---- scatter pipeline: bin -> scan -> reorder(LDS-clustered) -> accumulate --

// K1: per-block histogram over NB bins (bin = u>>2), int4-vectorized
__global__ __launch_bounds__(512) void hist_k(const int* __restrict__ ind,
                                              unsigned* __restrict__ cnt, int nnz) {
    __shared__ unsigned h[NB];
    const int tid = threadIdx.x;
    for (int i = tid; i < NB; i += 512) h[i] = 0u;
    __syncthreads();
    const int base = blockIdx.x * EPB;
    const int lim = min(nnz - base, EPB);
    const int4* ip = (const int4*)(ind + 2 * (size_t)base);
    for (int k2 = tid; k2 < lim / 2; k2 += 512) {
        int4 w = ip[k2];
        atomicAdd(&h[w.y >> 2], 1u);
        atomicAdd(&h[w.w >> 2], 1u);
    }
    if ((lim & 1) && tid == 0) {
        int u = ind[2 * (size_t)(base + lim - 1) + 1];
        atomicAdd(&h[u >> 2], 1u);
    }
    __syncthreads();
    for (int i = tid; i < NB; i += 512) cnt[(size_t)blockIdx.x * NB + i] = h[i];
}

// K2a: per-bin exclusive scan over blocks, in place on cnt; bin totals -> bb[bin]
__global__ void scanb_k(unsigned* cnt, unsigned* __restrict__ bb, int nblk) {
    __shared__ unsigned s[256];
    const int tid = threadIdx.x, bin = blockIdx.x;
    unsigned carry = 0;
    for (int c0 = 0; c0 < nblk; c0 += 256) {
        int b = c0 + tid;
        unsigned v = (b < nblk) ? cnt[(size_t)b * NB + bin] : 0u;
        s[tid] = v;
        __syncthreads();
        for (int off = 1; off < 256; off <<= 1) {
            unsigned add = (tid >= off) ? s[tid - off] : 0u;
            __syncthreads();
            s[tid] += add;
            __syncthreads();
        }
        if (b < nblk) cnt[(size_t)b * NB + bin] = carry + s[tid] - v;
        carry += s[255];
        __syncthreads();
    }
    if (tid == 0) bb[bin] = carry;
}

// K2b: exclusive scan of bin totals (single block, NB threads), bb[NB] = total
__global__ void scant_k(unsigned* bb) {
    __shared__ unsigned s[NB];
    const int tid = threadIdx.x;
    unsigned v = bb[tid];
    s[tid] = v;
    __syncthreads();
    for (int off = 1; off < NB; off <<= 1) {
        unsigned add = (tid >= off) ? s[tid - off] : 0u;
        __syncthreads();
        s[tid] += add;
        __syncthreads();
    }
    bb[tid] = s[tid] - v;
    if (tid == NB - 1) bb[NB] = s[tid];
}

// K3: LDS-clustered reorder — local hist+scan, scatter into LDS by bin,
// then run-coalesced writeout (avg 8-entry = 64B contiguous segments).
__global__ __launch_bounds__(512) void reorder_k(const int* __restrict__ ind,
                                                 const float* __restrict__ kv,
                                                 const unsigned* __restrict__ start,
                                                 const unsigned* __restrict__ bb,
                                                 uint2* __restrict__ ebuf, int nnz) {
    extern __shared__ char rsm[];
    uint2*    buf  = (uint2*)rsm;                 // 64 KB  entries clustered by bin
    unsigned* gofs = (unsigned*)(rsm + 65536);    // 32 KB  per-slot global position
    unsigned* cur  = (unsigned*)(rsm + 98304);    //  4 KB  hist -> cursor
    unsigned* dl   = (unsigned*)(rsm + 102400);   //  4 KB  global delta per bin
    unsigned* ss   = (unsigned*)(rsm + 106496);   //  2 KB  512 pair-sums for scan
    const int tid = threadIdx.x, blk = blockIdx.x;
    const int base = blk * EPB;
    const int lim = min(nnz - base, EPB);
    const int4*   ip = (const int4*)(ind + 2 * (size_t)base);
    const float2* vp = (const float2*)(kv + base);

    // 1) local hist
    for (int i = tid; i < NB; i += 512) cur[i] = 0u;
    __syncthreads();
    for (int k2 = tid; k2 < lim / 2; k2 += 512) {
        int4 w = ip[k2];
        atomicAdd(&cur[w.y >> 2], 1u);
        atomicAdd(&cur[w.w >> 2], 1u);
    }
    if ((lim & 1) && tid == 0) {
        int u = ind[2 * (size_t)(base + lim - 1) + 1];
        atomicAdd(&cur[u >> 2], 1u);
    }
    __syncthreads();
    // 2) exclusive scan over 1024 bins (2 bins/thread)
    unsigned c0 = cur[2 * tid], c1 = cur[2 * tid + 1];
    unsigned own = c0 + c1;
    ss[tid] = own;
    __syncthreads();
    for (int off = 1; off < 512; off <<= 1) {
        unsigned t = (tid >= off) ? ss[tid - off] : 0u;
        __syncthreads();
        ss[tid] += t;
        __syncthreads();
    }
    unsigned e0 = ss[tid] - own;
    unsigned e1 = e0 + c0;
    __syncthreads();
    cur[2 * tid]     = e0;
    cur[2 * tid + 1] = e1;
    unsigned g0 = bb[2 * tid]     + start[(size_t)blk * NB + 2 * tid];
    unsigned g1 = bb[2 * tid + 1] + start[(size_t)blk * NB + 2 * tid + 1];
    dl[2 * tid]     = g0 - e0;
    dl[2 * tid + 1] = g1 - e1;
    __syncthreads();
    // 3) scatter into LDS (random LDS, cheap)
    for (int k2 = tid; k2 < lim / 2; k2 += 512) {
        int4 w = ip[k2];
        float2 v = vp[k2];
        int b0 = w.y >> 2, b1 = w.w >> 2;
        unsigned r0 = atomicAdd(&cur[b0], 1u);
        buf[r0]  = make_uint2(((unsigned)(w.y & 3) << 13) | (unsigned)w.x, __float_as_uint(v.x));
        gofs[r0] = dl[b0] + r0;
        unsigned r1 = atomicAdd(&cur[b1], 1u);
        buf[r1]  = make_uint2(((unsigned)(w.w & 3) << 13) | (unsigned)w.z, __float_as_uint(v.y));
        gofs[r1] = dl[b1] + r1;
    }
    if ((lim & 1) && tid == 0) {
        size_t e = (size_t)base + lim - 1;
        int d = ind[2 * e], u = ind[2 * e + 1];
        int b = u >> 2;
        unsigned r = atomicAdd(&cur[b], 1u);
        buf[r]  = make_uint2(((unsigned)(u & 3) << 13) | (unsigned)d, __float_as_uint(kv[e]));
        gofs[r] = dl[b] + r;
    }
    __syncthreads();
    // 4) run-coalesced writeout
    for (int j = tid; j < lim; j += 512)
        ebuf[gofs[j]] = buf[j];
}

// K4: per-bin LDS fp32 accumulate + dense fp16 writeout (replaces zero-fill too)
__global__ __launch_bounds__(512) void accum_k(const uint2* __restrict__ ebuf,
                                               const unsigned* __restrict__ bb,
                                               Half4* __restrict__ wh4) {
    extern __shared__ float reg[];            // 32768 floats = 128 KB
    floatx4* reg4 = (floatx4*)reg;
    const int tid = threadIdx.x, bin = blockIdx.x;
    for (int i = tid; i < 8192; i += 512) reg4[i] = floatx4{0.f, 0.f, 0.f, 0.f};
    __syncthreads();
    const unsigned s0 = bb[bin], s1 = bb[bin + 1];
    for (unsigned e = s0 + tid; e < s1; e += 512) {
        uint2 p = ebuf[e];
        atomicAdd(&reg[p.x], __uint_as_float(p.y));   // ds_add_f32
    }
    __syncthreads();
    for (int i = tid; i < 8192; i += 512) {
        floatx4 f = reg4[i];
        Half4 h;
        h.a = __floats2half2_rn(f.x, f.y);
        h.b = __floats2half2_rn(f.z, f.w);
        wh4[(size_t)bin * 8192 + i] = h;
    }
}

// ---------------------------------------------------------------------------
// 256x256 split-K GEMM. Per K-tile: register-pipelined frag groups with
// COUNTED lgkmcnt waits (never a full drain until the last group):
//   issue{A0-3,B0,A4-7}(12) -> lgkm(4) -> MFMA G0 || issue ch1 G0 ->
//   lgkm(8) -> MFMA G1 || issue ch1 A4-7 -> lgkm(4) -> MFMA -> lgkm(0) -> MFMA.
// <=12 ds_reads outstanding (lgkmcnt is 4-bit). sched_barrier(0) after every
// counted wait (compiler hoists reg-only MFMA past asm lgkmcnt otherwise).
// Tile-level dbuf unchanged: raw s_barrier + STAGE + vmcnt(8).
// ---------------------------------------------------------------------------
__global__ __launch_bounds__(512, 2) void gemm8_k(
    const _Float16* __restrict__ Ah,   // [M][K] fp16
    const _Float16* __restrict__ Bh,   // [N][K] fp16
    float*          __restrict__ part) // [SPLIT][M][N] fp32
{
    extern __shared__ char smem[];

    const int tid  = threadIdx.x;
    const int lane = tid & 63;
    const int wave = tid >> 6;

    const int bid = blockIdx.x;
    const int swz = (bid & 7) * 32 + (bid >> 3);
    const int n0  = (swz >> 4) * 256;
    const int rem = swz & 15;
    const int m0  = (rem >> 2) * 256;
    const int sp  = rem & 3;
    const size_t kbase = (size_t)sp * KSPL;

    const int srow = tid >> 3;
    const int sch  = (tid & 7) ^ (srow & 7);
    const _Float16* aSg = Ah + (size_t)(m0 + srow) * DIM_K + kbase + sch * 8;
    const _Float16* bSg = Bh + (size_t)(n0 + srow) * DIM_K + kbase + sch * 8;
    char* aLg = smem + wave * 1024;
    char* bLg = smem + 32768 + wave * 1024;

    const int wn  = wave & 3;
    const int wrm = wave >> 2;
    const int q   = lane >> 4;
    const int l7  = lane & 7;
    const char* aRd = smem + (wrm * 128 + (lane & 15)) * 128;
    const char* bRd = smem + 32768 + (wn * 64 + (lane & 15)) * 128;
    const int ch0 = ((0 * 4 + q) ^ l7) * 16;
    const int ch1 = ((1 * 4 + q) ^ l7) * 16;

    floatx4 acc[8][4] = {};
    half8 a0[4], a1[4], a2[4], a3[4], b0[4], b1[4];

#define STAGE(C)                                                              \
    { _Pragma("unroll") for (int j = 0; j < 4; ++j) {                         \
        gload_lds16(aSg + (size_t)j * (64 * DIM_K), aLg + (C) * 65536 + j * 8192); \
        gload_lds16(bSg + (size_t)j * (64 * DIM_K), bLg + (C) * 65536 + j * 8192); } \
      aSg += BKT; bSg += BKT; }

#define RDA(dst, C, F0, CH)                                                   \
    { _Pragma("unroll") for (int i = 0; i < 4; ++i)                           \
        dst[i] = *(const half8*)(aRd + (C) * 65536 + ((F0) + i) * 2048 + (CH)); }
#define RDB(dst, C, CH)                                                       \
    { _Pragma("unroll") for (int i = 0; i < 4; ++i)                           \
        dst[i] = *(const half8*)(bRd + (C) * 65536 + i * 2048 + (CH)); }
#define WAITL(N)                                                              \
    asm volatile("s_waitcnt lgkmcnt(" #N ")" ::: "memory");                   \
    __builtin_amdgcn_sched_barrier(0);
#define MM(AA, BB, MOFF)                                                      \
    __builtin_amdgcn_s_setprio(1);                                            \
    _Pragma("unroll") for (int mi = 0; mi < 4; ++mi)                          \
      _Pragma("unroll") for (int ni = 0; ni < 4; ++ni)                        \
        acc[(MOFF) + mi][ni] = __builtin_amdgcn_mfma_f32_16x16x32_f16(        \
            AA[mi], BB[ni], acc[(MOFF) + mi][ni], 0, 0, 0);                   \
    __builtin_amdgcn_s_setprio(0);

#define KTILE(C)                                                              \
    RDA(a0, C, 0, ch0) RDB(b0, C, ch0) RDA(a1, C, 4, ch0)  /* 12 out */       \
    WAITL(4)  MM(a0, b0, 0)                                                   \
    RDA(a2, C, 0, ch1) RDB(b1, C, ch1)                     /* 4+8 = 12 out */ \
    WAITL(8)  MM(a1, b0, 4)                                                   \
    RDA(a3, C, 4, ch1)                                     /* 8+4 = 12 out */ \
    WAITL(4)  MM(a2, b1, 0)                                                   \
    WAITL(0)  MM(a3, b1, 4)

    // prologue: stage K-tiles 0,1; wait tile 0 (8 newest may stay in flight)
    STAGE(0)
    STAGE(1)
    asm volatile("s_waitcnt vmcnt(8)" ::: "memory");
    __builtin_amdgcn_s_barrier();

    for (int t2 = 0; t2 < NT / 2; ++t2) {
        KTILE(0)                                  // compute tile 2*t2 (buf0)
        __builtin_amdgcn_s_barrier();             // all waves done reading buf0
        if (t2 < NT / 2 - 1) {
            STAGE(0)                              // stage tile 2*t2+2 into buf0
            asm volatile("s_waitcnt vmcnt(8)" ::: "memory");  // tile 2*t2+1 landed
        } else {
            asm volatile("s_waitcnt vmcnt(0)" ::: "memory");  // last tile landed
        }
        __builtin_amdgcn_s_barrier();
        KTILE(1)                                  // compute tile 2*t2+1 (buf1)
        if (t2 < NT / 2 - 1) {
            __builtin_amdgcn_s_barrier();         // all waves done reading buf1
            STAGE(1)                              // stage tile 2*t2+3 into buf1
            asm volatile("s_waitcnt vmcnt(8)" ::: "memory");  // tile 2*t2+2 landed
            __builtin_amdgcn_s_barrier();
        }
    }

#undef KTILE
#undef MM
#undef WAITL
#undef RDB
#undef RDA
#undef STAGE

    // epilogue: raw partials (C/D layout: col = lane&15, row = q*4 + r)
    float* pbase = part + (size_t)sp * DIM_M * DIM_N;
    #pragma unroll
    for (int ni = 0; ni < 4; ++ni) {
        const int col = n0 + wn * 64 + ni * 16 + (lane & 15);
        #pragma unroll
        for (int mi = 0; mi < 8; ++mi) {
            const int row = m0 + wrm * 128 + mi * 16 + (q << 2);
            #pragma unroll
            for (int r = 0; r < 4; ++r)
                pbase[(size_t)(row + r) * DIM_N + col] = acc[mi][ni][r];
        }
    }
}

// out = tanh(sum_splits(part) + bias), vectorized float4
__global__ void reduce_tanh(const floatx4* __restrict__ part, const float* __restrict__ bias,
                            floatx4* __restrict__ out) {
    const int n4 = DIM_M * DIM_N / 4;
    int i = blockIdx.x * blockDim.x + threadIdx.x;
    if (i < n4) {
        floatx4 s = part[i];
        #pragma unroll
        for (int sp = 1; sp < SPLIT; ++sp)
            s += part[(size_t)sp * n4 + i];
        floatx4 b = ((const floatx4*)bias)[i & (DIM_N / 4 - 1)];
        floatx4 o;
        o.x = tanhf(s.x + b.x);
        o.y = tanhf(s.y + b.y);
        o.z = tanhf(s.z + b.z);
        o.w = tanhf(s.w + b.w);
        out[i] = o;
    }
}

extern "C" void kernel_launch(void* const* d_in, const int* in_sizes, int n_in,
                              void* d_out, int out_size, void* d_ws, size_t ws_size,
                              hipStream_t stream) {
    const float* x    = (const float*)d_in[0];
    const float* kv   = (const float*)d_in[1];
    const float* bias = (const float*)d_in[2];
    const int*   ind  = (const int*)d_in[3];
    float* out = (float*)d_out;
    const int nnz = in_sizes[1];

    char* ws = (char*)d_ws;
    _Float16* wh = (_Float16*)ws;                               // [N][K] fp16, 64 MB
    const size_t whBytes = (size_t)DIM_N * DIM_K * 2;
    _Float16* xh = (_Float16*)(ws + whBytes);                   // [M][K] fp16, 16 MB
    const size_t xhBytes = (size_t)DIM_M * DIM_K * 2;
    float* part = (float*)(ws + whBytes + xhBytes);             // [SPLIT][M][N] fp32, 64 MB
    const size_t partBytes = (size_t)SPLIT * DIM_M * DIM_N * 4;
    uint2* ebuf = (uint2*)(ws + whBytes + xhBytes + partBytes); // nnz*8 B (<=16 MB)
    const size_t ebufBytes = (size_t)16 << 20;
    unsigned* cnt = (unsigned*)(ws + whBytes + xhBytes + partBytes + ebufBytes); // 4 MB
    const size_t cntBytes = (size_t)1024 * NB * 4;
    unsigned* bb = (unsigned*)(ws + whBytes + xhBytes + partBytes + ebufBytes + cntBytes); // NB+1

    const int xN4 = (int)((size_t)DIM_M * DIM_K / 4);
    const int oN4 = DIM_M * DIM_N / 4;
    const int nblk = (nnz + EPB - 1) / EPB;

    cvt_f2h<<<(xN4 + 255) / 256, 256, 0, stream>>>((const floatx4*)x, (Half4*)xh, xN4);
    hist_k<<<nblk, 512, 0, stream>>>(ind, cnt, nnz);
    scanb_k<<<NB, 256, 0, stream>>>(cnt, bb, nblk);
    scant_k<<<1, NB, 0, stream>>>(bb);

    hipFuncSetAttribute((const void*)reorder_k,
                        hipFuncAttributeMaxDynamicSharedMemorySize, 131072);
    reorder_k<<<nblk, 512, 110592, stream>>>(ind, kv, cnt, bb, ebuf, nnz);

    hipFuncSetAttribute((const void*)accum_k,
                        hipFuncAttributeMaxDynamicSharedMemorySize, 131072);
    accum_k<<<NB, 512, 131072, stream>>>(ebuf, bb, (Half4*)wh);

    hipFuncSetAttribute((const void*)gemm8_k,
                        hipFuncAttributeMaxDynamicSharedMemorySize, 131072);
    gemm8_k<<<dim3(256), 512, 131072, stream>>>(xh, wh, part);

    reduce_tanh<<<(oN4 + 255) / 256, 256, 0, stream>>>((const floatx4*)part, bias, (floatx4*)out);
}

// Round 8
// 138.720 us; speedup vs baseline: 1.3905x; 1.0108x over previous
//
#include <hip/hip_runtime.h>
#include <hip/hip_fp16.h>
#include <cmath>

#define DIM_M 1024   // B (batch)
#define DIM_K 8192   // D
#define DIM_N 4096   // U
#define SPLIT 4
#define KSPL  (DIM_K / SPLIT)   // 2048
#define BKT   64
#define NT    (KSPL / BKT)      // 32 K-tiles per block
#define NB    1024              // scatter bins (4 u-rows = 128 KB fp32 region each)
#define EPB   8192              // entries per block in hist/reorder

typedef __attribute__((ext_vector_type(8))) _Float16 half8;
typedef __attribute__((ext_vector_type(4))) float floatx4;

struct __align__(8) Half4 { __half2 a, b; };

__device__ inline void gload_lds16(const void* g, void* l) {
    __builtin_amdgcn_global_load_lds(
        (const __attribute__((address_space(1))) void*)g,
        (__attribute__((address_space(3))) void*)l, 16, 0, 0);
}

__global__ void cvt_f2h(const floatx4* __restrict__ in, Half4* __restrict__ out, int n4) {
    int i = blockIdx.x * blockDim.x + threadIdx.x;
    if (i < n4) {
        floatx4 f = in[i];
        Half4 h;
        h.a = __floats2half2_rn(f.x, f.y);
        h.b = __floats2half2_rn(f.z, f.w);
        out[i] = h;
    }
}

// ---- scatter pipeline: bin -> scan -> reorder(LDS-clustered) -> accumulate --

// K1: per-block histogram over NB bins (bin = u>>2), int4-vectorized
__global__ __launch_bounds__(512) void hist_k(const int* __restrict__ ind,
                                              unsigned* __restrict__ cnt, int nnz) {
    __shared__ unsigned h[NB];
    const int tid = threadIdx.x;
    for (int i = tid; i < NB; i += 512) h[i] = 0u;
    __syncthreads();
    const int base = blockIdx.x * EPB;
    const int lim = min(nnz - base, EPB);
    const int4* ip = (const int4*)(ind + 2 * (size_t)base);
    for (int k2 = tid; k2 < lim / 2; k2 += 512) {
        int4 w = ip[k2];
        atomicAdd(&h[w.y >> 2], 1u);
        atomicAdd(&h[w.w >> 2], 1u);
    }
    if ((lim & 1) && tid == 0) {
        int u = ind[2 * (size_t)(base + lim - 1) + 1];
        atomicAdd(&h[u >> 2], 1u);
    }
    __syncthreads();
    for (int i = tid; i < NB; i += 512) cnt[(size_t)blockIdx.x * NB + i] = h[i];
}

// K2a: per-bin exclusive scan over blocks, in place on cnt; bin totals -> bb[bin]
__global__ void scanb_k(unsigned* cnt, unsigned* __restrict__ bb, int nblk) {
    __shared__ unsigned s[256];
    const int tid = threadIdx.x, bin = blockIdx.x;
    unsigned carry = 0;
    for (int c0 = 0; c0 < nblk; c0 += 256) {
        int b = c0 + tid;
        unsigned v = (b < nblk) ? cnt[(size_t)b * NB + bin] : 0u;
        s[tid] = v;
        __syncthreads();
        for (int off = 1; off < 256; off <<= 1) {
            unsigned add = (tid >= off) ? s[tid - off] : 0u;
            __syncthreads();
            s[tid] += add;
            __syncthreads();
        }
        if (b < nblk) cnt[(size_t)b * NB + bin] = carry + s[tid] - v;
        carry += s[255];
        __syncthreads();
    }
    if (tid == 0) bb[bin] = carry;
}

// K2b: exclusive scan of bin totals (single block, NB threads), bb[NB] = total
__global__ void scant_k(unsigned* bb) {
    __shared__ unsigned s[NB];
    const int tid = threadIdx.x;
    unsigned v = bb[tid];
    s[tid] = v;
    __syncthreads();
    for (int off = 1; off < NB; off <<= 1) {
        unsigned add = (tid >= off) ? s[tid - off] : 0u;
        __syncthreads();
        s[tid] += add;
        __syncthreads();
    }
    bb[tid] = s[tid] - v;
    if (tid == NB - 1) bb[NB] = s[tid];
}

// K3: LDS-clustered reorder — local hist+scan, scatter into LDS by bin,
// then run-coalesced writeout (avg 8-entry = 64B contiguous segments).
__global__ __launch_bounds__(512) void reorder_k(const int* __restrict__ ind,
                                                 const float* __restrict__ kv,
                                                 const unsigned* __restrict__ start,
                                                 const unsigned* __restrict__ bb,
                                                 uint2* __restrict__ ebuf, int nnz) {
    extern __shared__ char rsm[];
    uint2*    buf  = (uint2*)rsm;                 // 64 KB  entries clustered by bin
    unsigned* gofs = (unsigned*)(rsm + 65536);    // 32 KB  per-slot global position
    unsigned* cur  = (unsigned*)(rsm + 98304);    //  4 KB  hist -> cursor
    unsigned* dl   = (unsigned*)(rsm + 102400);   //  4 KB  global delta per bin
    unsigned* ss   = (unsigned*)(rsm + 106496);   //  2 KB  512 pair-sums for scan
    const int tid = threadIdx.x, blk = blockIdx.x;
    const int base = blk * EPB;
    const int lim = min(nnz - base, EPB);
    const int4*   ip = (const int4*)(ind + 2 * (size_t)base);
    const float2* vp = (const float2*)(kv + base);

    // 1) local hist
    for (int i = tid; i < NB; i += 512) cur[i] = 0u;
    __syncthreads();
    for (int k2 = tid; k2 < lim / 2; k2 += 512) {
        int4 w = ip[k2];
        atomicAdd(&cur[w.y >> 2], 1u);
        atomicAdd(&cur[w.w >> 2], 1u);
    }
    if ((lim & 1) && tid == 0) {
        int u = ind[2 * (size_t)(base + lim - 1) + 1];
        atomicAdd(&cur[u >> 2], 1u);
    }
    __syncthreads();
    // 2) exclusive scan over 1024 bins (2 bins/thread)
    unsigned c0 = cur[2 * tid], c1 = cur[2 * tid + 1];
    unsigned own = c0 + c1;
    ss[tid] = own;
    __syncthreads();
    for (int off = 1; off < 512; off <<= 1) {
        unsigned t = (tid >= off) ? ss[tid - off] : 0u;
        __syncthreads();
        ss[tid] += t;
        __syncthreads();
    }
    unsigned e0 = ss[tid] - own;
    unsigned e1 = e0 + c0;
    __syncthreads();
    cur[2 * tid]     = e0;
    cur[2 * tid + 1] = e1;
    unsigned g0 = bb[2 * tid]     + start[(size_t)blk * NB + 2 * tid];
    unsigned g1 = bb[2 * tid + 1] + start[(size_t)blk * NB + 2 * tid + 1];
    dl[2 * tid]     = g0 - e0;
    dl[2 * tid + 1] = g1 - e1;
    __syncthreads();
    // 3) scatter into LDS (random LDS, cheap)
    for (int k2 = tid; k2 < lim / 2; k2 += 512) {
        int4 w = ip[k2];
        float2 v = vp[k2];
        int b0 = w.y >> 2, b1 = w.w >> 2;
        unsigned r0 = atomicAdd(&cur[b0], 1u);
        buf[r0]  = make_uint2(((unsigned)(w.y & 3) << 13) | (unsigned)w.x, __float_as_uint(v.x));
        gofs[r0] = dl[b0] + r0;
        unsigned r1 = atomicAdd(&cur[b1], 1u);
        buf[r1]  = make_uint2(((unsigned)(w.w & 3) << 13) | (unsigned)w.z, __float_as_uint(v.y));
        gofs[r1] = dl[b1] + r1;
    }
    if ((lim & 1) && tid == 0) {
        size_t e = (size_t)base + lim - 1;
        int d = ind[2 * e], u = ind[2 * e + 1];
        int b = u >> 2;
        unsigned r = atomicAdd(&cur[b], 1u);
        buf[r]  = make_uint2(((unsigned)(u & 3) << 13) | (unsigned)d, __float_as_uint(kv[e]));
        gofs[r] = dl[b] + r;
    }
    __syncthreads();
    // 4) run-coalesced writeout
    for (int j = tid; j < lim; j += 512)
        ebuf[gofs[j]] = buf[j];
}

// K4: per-bin LDS fp32 accumulate + dense fp16 writeout (replaces zero-fill too)
__global__ __launch_bounds__(512) void accum_k(const uint2* __restrict__ ebuf,
                                               const unsigned* __restrict__ bb,
                                               Half4* __restrict__ wh4) {
    extern __shared__ float reg[];            // 32768 floats = 128 KB
    floatx4* reg4 = (floatx4*)reg;
    const int tid = threadIdx.x, bin = blockIdx.x;
    for (int i = tid; i < 8192; i += 512) reg4[i] = floatx4{0.f, 0.f, 0.f, 0.f};
    __syncthreads();
    const unsigned s0 = bb[bin], s1 = bb[bin + 1];
    for (unsigned e = s0 + tid; e < s1; e += 512) {
        uint2 p = ebuf[e];
        atomicAdd(&reg[p.x], __uint_as_float(p.y));   // ds_add_f32
    }
    __syncthreads();
    for (int i = tid; i < 8192; i += 512) {
        floatx4 f = reg4[i];
        Half4 h;
        h.a = __floats2half2_rn(f.x, f.y);
        h.b = __floats2half2_rn(f.z, f.w);
        wh4[(size_t)bin * 8192 + i] = h;
    }
}

// ---------------------------------------------------------------------------
// 256x256 split-K GEMM, 16 waves (1024 thr) of 64x64 each -> acc[4][4] = 64
// VGPR -> 4 waves/SIMD (vs 2 before): TLP overlaps LDS-port and MFMA pipes
// across waves instead of relying on intra-wave scheduling (R5/R6 null).
// Per K-tile: 2 phases {8 ds_read -> lgkm(0) -> 16 MFMA}, 1 barrier-pair,
// batched STAGE (4 gloads/thread), counted vmcnt(4). Raw s_barrier only.
// ---------------------------------------------------------------------------
__global__ __launch_bounds__(1024, 4) void gemm8_k(
    const _Float16* __restrict__ Ah,   // [M][K] fp16
    const _Float16* __restrict__ Bh,   // [N][K] fp16
    float*          __restrict__ part) // [SPLIT][M][N] fp32
{
    extern __shared__ char smem[];

    const int tid  = threadIdx.x;
    const int lane = tid & 63;
    const int wave = tid >> 6;           // 0..15

    const int bid = blockIdx.x;
    const int swz = (bid & 7) * 32 + (bid >> 3);
    const int n0  = (swz >> 4) * 256;
    const int rem = swz & 15;
    const int m0  = (rem >> 2) * 256;
    const int sp  = rem & 3;
    const size_t kbase = (size_t)sp * KSPL;

    // staging: slot s = p*1024 + tid (p=0,1): row = p*128 + tid>>3, chunk tid&7,
    // source chunk pre-swizzled ^(row&7) = ^((tid>>3)&7)  (128 = 0 mod 8).
    const int srow = tid >> 3;                   // 0..127
    const int sch  = (tid & 7) ^ (srow & 7);
    const _Float16* aSg = Ah + (size_t)(m0 + srow) * DIM_K + kbase + sch * 8;
    const _Float16* bSg = Bh + (size_t)(n0 + srow) * DIM_K + kbase + sch * 8;
    char* aLg = smem + wave * 1024;              // + C*65536 + p*16384
    char* bLg = smem + 32768 + wave * 1024;

    // read side: 16 waves as 4x4; wave tile 64x64.
    const int wn  = wave & 3;            // N quadrant
    const int wrm = wave >> 2;           // M quadrant
    const int q   = lane >> 4;
    const int l7  = lane & 7;
    const char* aRd = smem + (wrm * 64 + (lane & 15)) * 128;
    const char* bRd = smem + 32768 + (wn * 64 + (lane & 15)) * 128;
    const int ch0 = ((0 * 4 + q) ^ l7) * 16;
    const int ch1 = ((1 * 4 + q) ^ l7) * 16;

    floatx4 acc[4][4] = {};
    half8 aF[4], bF[4];

#define STAGE(C)                                                              \
    { _Pragma("unroll") for (int p = 0; p < 2; ++p) {                         \
        gload_lds16(aSg + (size_t)p * (128 * DIM_K), aLg + (C) * 65536 + p * 16384); \
        gload_lds16(bSg + (size_t)p * (128 * DIM_K), bLg + (C) * 65536 + p * 16384); } \
      aSg += BKT; bSg += BKT; }

#define PH(C, CH)                                                             \
    { _Pragma("unroll") for (int i = 0; i < 4; ++i)                           \
        aF[i] = *(const half8*)(aRd + (C) * 65536 + i * 2048 + (CH));         \
      _Pragma("unroll") for (int i = 0; i < 4; ++i)                           \
        bF[i] = *(const half8*)(bRd + (C) * 65536 + i * 2048 + (CH));         \
      asm volatile("s_waitcnt lgkmcnt(0)" ::: "memory");                      \
      __builtin_amdgcn_sched_barrier(0);                                      \
      __builtin_amdgcn_s_setprio(1);                                          \
      _Pragma("unroll") for (int mi = 0; mi < 4; ++mi)                        \
        _Pragma("unroll") for (int ni = 0; ni < 4; ++ni)                      \
          acc[mi][ni] = __builtin_amdgcn_mfma_f32_16x16x32_f16(               \
              aF[mi], bF[ni], acc[mi][ni], 0, 0, 0);                          \
      __builtin_amdgcn_s_setprio(0); }

#define KTILE(C) PH(C, ch0) PH(C, ch1)

    // prologue: stage K-tiles 0,1; wait tile 0 (4 newest may stay in flight)
    STAGE(0)
    STAGE(1)
    asm volatile("s_waitcnt vmcnt(4)" ::: "memory");
    __builtin_amdgcn_s_barrier();

    for (int t2 = 0; t2 < NT / 2; ++t2) {
        KTILE(0)                                  // compute tile 2*t2 (buf0)
        __builtin_amdgcn_s_barrier();             // all waves done reading buf0
        if (t2 < NT / 2 - 1) {
            STAGE(0)                              // stage tile 2*t2+2 into buf0
            asm volatile("s_waitcnt vmcnt(4)" ::: "memory");  // tile 2*t2+1 landed
        } else {
            asm volatile("s_waitcnt vmcnt(0)" ::: "memory");  // last tile landed
        }
        __builtin_amdgcn_s_barrier();
        KTILE(1)                                  // compute tile 2*t2+1 (buf1)
        if (t2 < NT / 2 - 1) {
            __builtin_amdgcn_s_barrier();         // all waves done reading buf1
            STAGE(1)                              // stage tile 2*t2+3 into buf1
            asm volatile("s_waitcnt vmcnt(4)" ::: "memory");  // tile 2*t2+2 landed
            __builtin_amdgcn_s_barrier();
        }
    }

#undef KTILE
#undef PH
#undef STAGE

    // epilogue: raw partials (C/D layout: col = lane&15, row = q*4 + r)
    float* pbase = part + (size_t)sp * DIM_M * DIM_N;
    #pragma unroll
    for (int ni = 0; ni < 4; ++ni) {
        const int col = n0 + wn * 64 + ni * 16 + (lane & 15);
        #pragma unroll
        for (int mi = 0; mi < 4; ++mi) {
            const int row = m0 + wrm * 64 + mi * 16 + (q << 2);
            #pragma unroll
            for (int r = 0; r < 4; ++r)
                pbase[(size_t)(row + r) * DIM_N + col] = acc[mi][ni][r];
        }
    }
}

// out = tanh(sum_splits(part) + bias), vectorized float4
__global__ void reduce_tanh(const floatx4* __restrict__ part, const float* __restrict__ bias,
                            floatx4* __restrict__ out) {
    const int n4 = DIM_M * DIM_N / 4;
    int i = blockIdx.x * blockDim.x + threadIdx.x;
    if (i < n4) {
        floatx4 s = part[i];
        #pragma unroll
        for (int sp = 1; sp < SPLIT; ++sp)
            s += part[(size_t)sp * n4 + i];
        floatx4 b = ((const floatx4*)bias)[i & (DIM_N / 4 - 1)];
        floatx4 o;
        o.x = tanhf(s.x + b.x);
        o.y = tanhf(s.y + b.y);
        o.z = tanhf(s.z + b.z);
        o.w = tanhf(s.w + b.w);
        out[i] = o;
    }
}

extern "C" void kernel_launch(void* const* d_in, const int* in_sizes, int n_in,
                              void* d_out, int out_size, void* d_ws, size_t ws_size,
                              hipStream_t stream) {
    const float* x    = (const float*)d_in[0];
    const float* kv   = (const float*)d_in[1];
    const float* bias = (const float*)d_in[2];
    const int*   ind  = (const int*)d_in[3];
    float* out = (float*)d_out;
    const int nnz = in_sizes[1];

    char* ws = (char*)d_ws;
    _Float16* wh = (_Float16*)ws;                               // [N][K] fp16, 64 MB
    const size_t whBytes = (size_t)DIM_N * DIM_K * 2;
    _Float16* xh = (_Float16*)(ws + whBytes);                   // [M][K] fp16, 16 MB
    const size_t xhBytes = (size_t)DIM_M * DIM_K * 2;
    float* part = (float*)(ws + whBytes + xhBytes);             // [SPLIT][M][N] fp32, 64 MB
    const size_t partBytes = (size_t)SPLIT * DIM_M * DIM_N * 4;
    uint2* ebuf = (uint2*)(ws + whBytes + xhBytes + partBytes); // nnz*8 B (<=16 MB)
    const size_t ebufBytes = (size_t)16 << 20;
    unsigned* cnt = (unsigned*)(ws + whBytes + xhBytes + partBytes + ebufBytes); // 4 MB
    const size_t cntBytes = (size_t)1024 * NB * 4;
    unsigned* bb = (unsigned*)(ws + whBytes + xhBytes + partBytes + ebufBytes + cntBytes); // NB+1

    const int xN4 = (int)((size_t)DIM_M * DIM_K / 4);
    const int oN4 = DIM_M * DIM_N / 4;
    const int nblk = (nnz + EPB - 1) / EPB;

    cvt_f2h<<<(xN4 + 255) / 256, 256, 0, stream>>>((const floatx4*)x, (Half4*)xh, xN4);
    hist_k<<<nblk, 512, 0, stream>>>(ind, cnt, nnz);
    scanb_k<<<NB, 256, 0, stream>>>(cnt, bb, nblk);
    scant_k<<<1, NB, 0, stream>>>(bb);

    hipFuncSetAttribute((const void*)reorder_k,
                        hipFuncAttributeMaxDynamicSharedMemorySize, 131072);
    reorder_k<<<nblk, 512, 110592, stream>>>(ind, kv, cnt, bb, ebuf, nnz);

    hipFuncSetAttribute((const void*)accum_k,
                        hipFuncAttributeMaxDynamicSharedMemorySize, 131072);
    accum_k<<<NB, 512, 131072, stream>>>(ebuf, bb, (Half4*)wh);

    hipFuncSetAttribute((const void*)gemm8_k,
                        hipFuncAttributeMaxDynamicSharedMemorySize, 131072);
    gemm8_k<<<dim3(256), 1024, 131072, stream>>>(xh, wh, part);

    reduce_tanh<<<(oN4 + 255) / 256, 256, 0, stream>>>((const floatx4*)part, bias, (floatx4*)out);
}

// Round 9
// 131.773 us; speedup vs baseline: 1.4639x; 1.0527x over previous
//
#include <hip/hip_runtime.h>
#include <hip/hip_fp16.h>
#include <cmath>

#define DIM_M 1024   // B (batch)
#define DIM_K 8192   // D
#define DIM_N 4096   // U
#define SPLIT 4
#define KSPL  (DIM_K / SPLIT)   // 2048
#define BKT   64
#define NT    (KSPL / BKT)      // 32 K-tiles per block
#define NB    1024              // scatter bins (4 u-rows = 128 KB fp32 region each)
#define EPB   8192              // entries per block in hist/reorder

typedef __attribute__((ext_vector_type(8))) _Float16 half8;
typedef __attribute__((ext_vector_type(4))) float floatx4;

struct __align__(8) Half4 { __half2 a, b; };

__device__ inline void gload_lds16(const void* g, void* l) {
    __builtin_amdgcn_global_load_lds(
        (const __attribute__((address_space(1))) void*)g,
        (__attribute__((address_space(3))) void*)l, 16, 0, 0);
}

__global__ void cvt_f2h(const floatx4* __restrict__ in, Half4* __restrict__ out, int n4) {
    int i = blockIdx.x * blockDim.x + threadIdx.x;
    if (i < n4) {
        floatx4 f = in[i];
        Half4 h;
        h.a = __floats2half2_rn(f.x, f.y);
        h.b = __floats2half2_rn(f.z, f.w);
        out[i] = h;
    }
}

// ---- scatter pipeline: bin -> scan -> reorder(LDS-clustered) -> accumulate --

// K1: per-block histogram over NB bins (bin = u>>2), int4-vectorized
__global__ __launch_bounds__(512) void hist_k(const int* __restrict__ ind,
                                              unsigned* __restrict__ cnt, int nnz) {
    __shared__ unsigned h[NB];
    const int tid = threadIdx.x;
    for (int i = tid; i < NB; i += 512) h[i] = 0u;
    __syncthreads();
    const int base = blockIdx.x * EPB;
    const int lim = min(nnz - base, EPB);
    const int4* ip = (const int4*)(ind + 2 * (size_t)base);
    for (int k2 = tid; k2 < lim / 2; k2 += 512) {
        int4 w = ip[k2];
        atomicAdd(&h[w.y >> 2], 1u);
        atomicAdd(&h[w.w >> 2], 1u);
    }
    if ((lim & 1) && tid == 0) {
        int u = ind[2 * (size_t)(base + lim - 1) + 1];
        atomicAdd(&h[u >> 2], 1u);
    }
    __syncthreads();
    for (int i = tid; i < NB; i += 512) cnt[(size_t)blockIdx.x * NB + i] = h[i];
}

// K2a: per-bin exclusive scan over blocks, in place on cnt; bin totals -> bb[bin]
__global__ void scanb_k(unsigned* cnt, unsigned* __restrict__ bb, int nblk) {
    __shared__ unsigned s[256];
    const int tid = threadIdx.x, bin = blockIdx.x;
    unsigned carry = 0;
    for (int c0 = 0; c0 < nblk; c0 += 256) {
        int b = c0 + tid;
        unsigned v = (b < nblk) ? cnt[(size_t)b * NB + bin] : 0u;
        s[tid] = v;
        __syncthreads();
        for (int off = 1; off < 256; off <<= 1) {
            unsigned add = (tid >= off) ? s[tid - off] : 0u;
            __syncthreads();
            s[tid] += add;
            __syncthreads();
        }
        if (b < nblk) cnt[(size_t)b * NB + bin] = carry + s[tid] - v;
        carry += s[255];
        __syncthreads();
    }
    if (tid == 0) bb[bin] = carry;
}

// K2b: exclusive scan of bin totals (single block, NB threads), bb[NB] = total
__global__ void scant_k(unsigned* bb) {
    __shared__ unsigned s[NB];
    const int tid = threadIdx.x;
    unsigned v = bb[tid];
    s[tid] = v;
    __syncthreads();
    for (int off = 1; off < NB; off <<= 1) {
        unsigned add = (tid >= off) ? s[tid - off] : 0u;
        __syncthreads();
        s[tid] += add;
        __syncthreads();
    }
    bb[tid] = s[tid] - v;
    if (tid == NB - 1) bb[NB] = s[tid];
}

// K3: LDS-clustered reorder — local hist+scan, scatter into LDS by bin,
// then run-coalesced writeout (avg 8-entry = 64B contiguous segments).
__global__ __launch_bounds__(512) void reorder_k(const int* __restrict__ ind,
                                                 const float* __restrict__ kv,
                                                 const unsigned* __restrict__ start,
                                                 const unsigned* __restrict__ bb,
                                                 uint2* __restrict__ ebuf, int nnz) {
    extern __shared__ char rsm[];
    uint2*    buf  = (uint2*)rsm;                 // 64 KB  entries clustered by bin
    unsigned* gofs = (unsigned*)(rsm + 65536);    // 32 KB  per-slot global position
    unsigned* cur  = (unsigned*)(rsm + 98304);    //  4 KB  hist -> cursor
    unsigned* dl   = (unsigned*)(rsm + 102400);   //  4 KB  global delta per bin
    unsigned* ss   = (unsigned*)(rsm + 106496);   //  2 KB  512 pair-sums for scan
    const int tid = threadIdx.x, blk = blockIdx.x;
    const int base = blk * EPB;
    const int lim = min(nnz - base, EPB);
    const int4*   ip = (const int4*)(ind + 2 * (size_t)base);
    const float2* vp = (const float2*)(kv + base);

    // 1) local hist
    for (int i = tid; i < NB; i += 512) cur[i] = 0u;
    __syncthreads();
    for (int k2 = tid; k2 < lim / 2; k2 += 512) {
        int4 w = ip[k2];
        atomicAdd(&cur[w.y >> 2], 1u);
        atomicAdd(&cur[w.w >> 2], 1u);
    }
    if ((lim & 1) && tid == 0) {
        int u = ind[2 * (size_t)(base + lim - 1) + 1];
        atomicAdd(&cur[u >> 2], 1u);
    }
    __syncthreads();
    // 2) exclusive scan over 1024 bins (2 bins/thread)
    unsigned c0 = cur[2 * tid], c1 = cur[2 * tid + 1];
    unsigned own = c0 + c1;
    ss[tid] = own;
    __syncthreads();
    for (int off = 1; off < 512; off <<= 1) {
        unsigned t = (tid >= off) ? ss[tid - off] : 0u;
        __syncthreads();
        ss[tid] += t;
        __syncthreads();
    }
    unsigned e0 = ss[tid] - own;
    unsigned e1 = e0 + c0;
    __syncthreads();
    cur[2 * tid]     = e0;
    cur[2 * tid + 1] = e1;
    unsigned g0 = bb[2 * tid]     + start[(size_t)blk * NB + 2 * tid];
    unsigned g1 = bb[2 * tid + 1] + start[(size_t)blk * NB + 2 * tid + 1];
    dl[2 * tid]     = g0 - e0;
    dl[2 * tid + 1] = g1 - e1;
    __syncthreads();
    // 3) scatter into LDS (random LDS, cheap)
    for (int k2 = tid; k2 < lim / 2; k2 += 512) {
        int4 w = ip[k2];
        float2 v = vp[k2];
        int b0 = w.y >> 2, b1 = w.w >> 2;
        unsigned r0 = atomicAdd(&cur[b0], 1u);
        buf[r0]  = make_uint2(((unsigned)(w.y & 3) << 13) | (unsigned)w.x, __float_as_uint(v.x));
        gofs[r0] = dl[b0] + r0;
        unsigned r1 = atomicAdd(&cur[b1], 1u);
        buf[r1]  = make_uint2(((unsigned)(w.w & 3) << 13) | (unsigned)w.z, __float_as_uint(v.y));
        gofs[r1] = dl[b1] + r1;
    }
    if ((lim & 1) && tid == 0) {
        size_t e = (size_t)base + lim - 1;
        int d = ind[2 * e], u = ind[2 * e + 1];
        int b = u >> 2;
        unsigned r = atomicAdd(&cur[b], 1u);
        buf[r]  = make_uint2(((unsigned)(u & 3) << 13) | (unsigned)d, __float_as_uint(kv[e]));
        gofs[r] = dl[b] + r;
    }
    __syncthreads();
    // 4) run-coalesced writeout
    for (int j = tid; j < lim; j += 512)
        ebuf[gofs[j]] = buf[j];
}

// K4: per-bin LDS fp32 accumulate + dense fp16 writeout (replaces zero-fill too)
__global__ __launch_bounds__(512) void accum_k(const uint2* __restrict__ ebuf,
                                               const unsigned* __restrict__ bb,
                                               Half4* __restrict__ wh4) {
    extern __shared__ float reg[];            // 32768 floats = 128 KB
    floatx4* reg4 = (floatx4*)reg;
    const int tid = threadIdx.x, bin = blockIdx.x;
    for (int i = tid; i < 8192; i += 512) reg4[i] = floatx4{0.f, 0.f, 0.f, 0.f};
    __syncthreads();
    const unsigned s0 = bb[bin], s1 = bb[bin + 1];
    for (unsigned e = s0 + tid; e < s1; e += 512) {
        uint2 p = ebuf[e];
        atomicAdd(&reg[p.x], __uint_as_float(p.y));   // ds_add_f32
    }
    __syncthreads();
    for (int i = tid; i < 8192; i += 512) {
        floatx4 f = reg4[i];
        Half4 h;
        h.a = __floats2half2_rn(f.x, f.y);
        h.b = __floats2half2_rn(f.z, f.w);
        wh4[(size_t)bin * 8192 + i] = h;
    }
}

// ---------------------------------------------------------------------------
// 256x256 split-K GEMM, 16 waves (1024 thr), 64x64 wave tile, 4 waves/SIMD.
// NEW: wave-parity phase STAGGER — even waves consume {ch0,ch1}, odd waves
// {ch1,ch0}. Both chunks of a landed tile are read-only, so order is free;
// the anti-phase keeps ~half the waves on the LDS port while the other half
// feeds the matrix pipe (R5/R6/R7 showed lockstep waves serialize the two).
// Partials now written as fp16 (|p|<~2, rounding ~5e-4 << error budget).
// ---------------------------------------------------------------------------
__global__ __launch_bounds__(1024, 4) void gemm8_k(
    const _Float16* __restrict__ Ah,   // [M][K] fp16
    const _Float16* __restrict__ Bh,   // [N][K] fp16
    _Float16*       __restrict__ part) // [SPLIT][M][N] fp16
{
    extern __shared__ char smem[];

    const int tid  = threadIdx.x;
    const int lane = tid & 63;
    const int wave = tid >> 6;           // 0..15

    const int bid = blockIdx.x;
    const int swz = (bid & 7) * 32 + (bid >> 3);
    const int n0  = (swz >> 4) * 256;
    const int rem = swz & 15;
    const int m0  = (rem >> 2) * 256;
    const int sp  = rem & 3;
    const size_t kbase = (size_t)sp * KSPL;

    const int srow = tid >> 3;                   // 0..127
    const int sch  = (tid & 7) ^ (srow & 7);
    const _Float16* aSg = Ah + (size_t)(m0 + srow) * DIM_K + kbase + sch * 8;
    const _Float16* bSg = Bh + (size_t)(n0 + srow) * DIM_K + kbase + sch * 8;
    char* aLg = smem + wave * 1024;              // + C*65536 + p*16384
    char* bLg = smem + 32768 + wave * 1024;

    const int wn  = wave & 3;            // N quadrant
    const int wrm = wave >> 2;           // M quadrant
    const int q   = lane >> 4;
    const int l7  = lane & 7;
    const char* aRd = smem + (wrm * 64 + (lane & 15)) * 128;
    const char* bRd = smem + 32768 + (wn * 64 + (lane & 15)) * 128;
    const int ch0 = ((0 * 4 + q) ^ l7) * 16;
    const int ch1 = ((1 * 4 + q) ^ l7) * 16;
    // wave-parity stagger: odd waves consume chunks in reverse order
    const int chA = (wave & 1) ? ch1 : ch0;
    const int chB = (wave & 1) ? ch0 : ch1;

    floatx4 acc[4][4] = {};
    half8 aF[4], bF[4];

#define STAGE(C)                                                              \
    { _Pragma("unroll") for (int p = 0; p < 2; ++p) {                         \
        gload_lds16(aSg + (size_t)p * (128 * DIM_K), aLg + (C) * 65536 + p * 16384); \
        gload_lds16(bSg + (size_t)p * (128 * DIM_K), bLg + (C) * 65536 + p * 16384); } \
      aSg += BKT; bSg += BKT; }

#define PH(C, CH)                                                             \
    { _Pragma("unroll") for (int i = 0; i < 4; ++i)                           \
        aF[i] = *(const half8*)(aRd + (C) * 65536 + i * 2048 + (CH));         \
      _Pragma("unroll") for (int i = 0; i < 4; ++i)                           \
        bF[i] = *(const half8*)(bRd + (C) * 65536 + i * 2048 + (CH));         \
      asm volatile("s_waitcnt lgkmcnt(0)" ::: "memory");                      \
      __builtin_amdgcn_sched_barrier(0);                                      \
      __builtin_amdgcn_s_setprio(1);                                          \
      _Pragma("unroll") for (int mi = 0; mi < 4; ++mi)                        \
        _Pragma("unroll") for (int ni = 0; ni < 4; ++ni)                      \
          acc[mi][ni] = __builtin_amdgcn_mfma_f32_16x16x32_f16(               \
              aF[mi], bF[ni], acc[mi][ni], 0, 0, 0);                          \
      __builtin_amdgcn_s_setprio(0); }

#define KTILE(C) PH(C, chA) PH(C, chB)

    // prologue: stage K-tiles 0,1; wait tile 0 (4 newest may stay in flight)
    STAGE(0)
    STAGE(1)
    asm volatile("s_waitcnt vmcnt(4)" ::: "memory");
    __builtin_amdgcn_s_barrier();

    for (int t2 = 0; t2 < NT / 2; ++t2) {
        KTILE(0)                                  // compute tile 2*t2 (buf0)
        __builtin_amdgcn_s_barrier();             // all waves done reading buf0
        if (t2 < NT / 2 - 1) {
            STAGE(0)                              // stage tile 2*t2+2 into buf0
            asm volatile("s_waitcnt vmcnt(4)" ::: "memory");  // tile 2*t2+1 landed
        } else {
            asm volatile("s_waitcnt vmcnt(0)" ::: "memory");  // last tile landed
        }
        __builtin_amdgcn_s_barrier();
        KTILE(1)                                  // compute tile 2*t2+1 (buf1)
        if (t2 < NT / 2 - 1) {
            __builtin_amdgcn_s_barrier();         // all waves done reading buf1
            STAGE(1)                              // stage tile 2*t2+3 into buf1
            asm volatile("s_waitcnt vmcnt(4)" ::: "memory");  // tile 2*t2+2 landed
            __builtin_amdgcn_s_barrier();
        }
    }

#undef KTILE
#undef PH
#undef STAGE

    // epilogue: fp16 partials (C/D layout: col = lane&15, row = q*4 + r)
    _Float16* pbase = part + (size_t)sp * DIM_M * DIM_N;
    #pragma unroll
    for (int ni = 0; ni < 4; ++ni) {
        const int col = n0 + wn * 64 + ni * 16 + (lane & 15);
        #pragma unroll
        for (int mi = 0; mi < 4; ++mi) {
            const int row = m0 + wrm * 64 + mi * 16 + (q << 2);
            #pragma unroll
            for (int r = 0; r < 4; ++r)
                pbase[(size_t)(row + r) * DIM_N + col] = (_Float16)acc[mi][ni][r];
        }
    }
}

// out = tanh(sum_splits(fp16 part) + bias), 4 outputs/thread
__global__ void reduce_tanh(const Half4* __restrict__ part, const float* __restrict__ bias,
                            floatx4* __restrict__ out) {
    const int n4 = DIM_M * DIM_N / 4;
    int i = blockIdx.x * blockDim.x + threadIdx.x;
    if (i < n4) {
        float sx = 0.f, sy = 0.f, sz = 0.f, sw = 0.f;
        #pragma unroll
        for (int sp = 0; sp < SPLIT; ++sp) {
            Half4 p = part[(size_t)sp * n4 + i];
            float2 lo = __half22float2(p.a);
            float2 hi = __half22float2(p.b);
            sx += lo.x; sy += lo.y; sz += hi.x; sw += hi.y;
        }
        floatx4 b = ((const floatx4*)bias)[i & (DIM_N / 4 - 1)];
        floatx4 o;
        o.x = tanhf(sx + b.x);
        o.y = tanhf(sy + b.y);
        o.z = tanhf(sz + b.z);
        o.w = tanhf(sw + b.w);
        out[i] = o;
    }
}

extern "C" void kernel_launch(void* const* d_in, const int* in_sizes, int n_in,
                              void* d_out, int out_size, void* d_ws, size_t ws_size,
                              hipStream_t stream) {
    const float* x    = (const float*)d_in[0];
    const float* kv   = (const float*)d_in[1];
    const float* bias = (const float*)d_in[2];
    const int*   ind  = (const int*)d_in[3];
    float* out = (float*)d_out;
    const int nnz = in_sizes[1];

    char* ws = (char*)d_ws;
    _Float16* wh = (_Float16*)ws;                               // [N][K] fp16, 64 MB
    const size_t whBytes = (size_t)DIM_N * DIM_K * 2;
    _Float16* xh = (_Float16*)(ws + whBytes);                   // [M][K] fp16, 16 MB
    const size_t xhBytes = (size_t)DIM_M * DIM_K * 2;
    _Float16* part = (_Float16*)(ws + whBytes + xhBytes);       // [SPLIT][M][N] fp16, 32 MB
    const size_t partBytes = (size_t)SPLIT * DIM_M * DIM_N * 2;
    uint2* ebuf = (uint2*)(ws + whBytes + xhBytes + partBytes); // nnz*8 B (<=16 MB)
    const size_t ebufBytes = (size_t)16 << 20;
    unsigned* cnt = (unsigned*)(ws + whBytes + xhBytes + partBytes + ebufBytes); // 4 MB
    const size_t cntBytes = (size_t)1024 * NB * 4;
    unsigned* bb = (unsigned*)(ws + whBytes + xhBytes + partBytes + ebufBytes + cntBytes); // NB+1

    const int xN4 = (int)((size_t)DIM_M * DIM_K / 4);
    const int oN4 = DIM_M * DIM_N / 4;
    const int nblk = (nnz + EPB - 1) / EPB;

    cvt_f2h<<<(xN4 + 255) / 256, 256, 0, stream>>>((const floatx4*)x, (Half4*)xh, xN4);
    hist_k<<<nblk, 512, 0, stream>>>(ind, cnt, nnz);
    scanb_k<<<NB, 256, 0, stream>>>(cnt, bb, nblk);
    scant_k<<<1, NB, 0, stream>>>(bb);

    hipFuncSetAttribute((const void*)reorder_k,
                        hipFuncAttributeMaxDynamicSharedMemorySize, 131072);
    reorder_k<<<nblk, 512, 110592, stream>>>(ind, kv, cnt, bb, ebuf, nnz);

    hipFuncSetAttribute((const void*)accum_k,
                        hipFuncAttributeMaxDynamicSharedMemorySize, 131072);
    accum_k<<<NB, 512, 131072, stream>>>(ebuf, bb, (Half4*)wh);

    hipFuncSetAttribute((const void*)gemm8_k,
                        hipFuncAttributeMaxDynamicSharedMemorySize, 131072);
    gemm8_k<<<dim3(256), 1024, 131072, stream>>>(xh, wh, part);

    reduce_tanh<<<(oN4 + 255) / 256, 256, 0, stream>>>((const Half4*)part, bias, (floatx4*)out);
}